// Round 1
// baseline (846.015 us; speedup 1.0000x reference)
//
#include <hip/hip_runtime.h>
#include <hip/hip_bf16.h>

#define S 4
#define N 32768
#define D 256
#define KSEG 512
#define NH 4
#define HD 64
#define FF 1024

typedef __attribute__((ext_vector_type(8))) short short8;
typedef __attribute__((ext_vector_type(4))) float f32x4;
typedef __attribute__((ext_vector_type(4))) unsigned int u32x4;
typedef __attribute__((ext_vector_type(2))) unsigned int u32x2;

__device__ __forceinline__ unsigned short f2bf(float f) {
  union { __hip_bfloat16 h; unsigned short u; } cv;
  cv.h = __float2bfloat16(f);
  return cv.u;
}

__device__ __forceinline__ float gelu_f(float x) {
  return 0.5f * x * (1.0f + erff(x * 0.70710678118654752440f));
}

__device__ __forceinline__ float wave_reduce_sum(float v) {
  #pragma unroll
  for (int o = 32; o > 0; o >>= 1) v += __shfl_xor(v, o, 64);
  return v;
}

// ---------------- Phase A: segment-mean pooling ----------------
// grid: S * 8 dslices * 8 chunks = 256 blocks, 256 threads
#define NCHUNK 8
__global__ __launch_bounds__(256) void pool_kernel(
    const float* __restrict__ H, const int* __restrict__ pids,
    float* __restrict__ sums, float* __restrict__ counts)
{
  __shared__ float acc[KSEG * 32];  // 64KB
  __shared__ float cnt[KSEG];
  int t = threadIdx.x;
  int b = blockIdx.x;
  int chunk = b & 7, ds = (b >> 3) & 7, s = b >> 6;
  for (int i = t; i < KSEG * 32; i += 256) acc[i] = 0.f;
  if (ds == 0) for (int i = t; i < KSEG; i += 256) cnt[i] = 0.f;
  __syncthreads();
  int d0 = ds * 32;
  int dlane = t & 31, nsub = t >> 5;
  int n0 = chunk * (N / NCHUNK);
  for (int i = 0; i < N / NCHUNK; i += 32) {
    int pid[4]; float h[4];
    #pragma unroll
    for (int u = 0; u < 4; u++) {
      int n = n0 + i + u * 8 + nsub;
      pid[u] = pids[s * N + n];
      h[u] = H[((size_t)(s * N + n)) * D + d0 + dlane];
    }
    #pragma unroll
    for (int u = 0; u < 4; u++) {
      atomicAdd(&acc[pid[u] * 32 + dlane], h[u]);
      if (ds == 0 && dlane == 0) atomicAdd(&cnt[pid[u]], 1.f);
    }
  }
  __syncthreads();
  for (int i = t; i < KSEG * 32; i += 256) {
    float v = acc[i];
    if (v != 0.f) atomicAdd(&sums[((size_t)(s * KSEG + (i >> 5))) * D + d0 + (i & 31)], v);
  }
  if (ds == 0) {
    for (int i = t; i < KSEG; i += 256) {
      float c = cnt[i];
      if (c != 0.f) atomicAdd(&counts[s * KSEG + i], c);
    }
  }
}

// x = sums / max(counts,1)   grid 2048x256
__global__ __launch_bounds__(256) void finalize_kernel(
    const float* __restrict__ sums, const float* __restrict__ counts,
    float* __restrict__ x)
{
  int i = blockIdx.x * 256 + threadIdx.x;
  float c = counts[i >> 8];
  x[i] = sums[i] / fmaxf(c, 1.f);
}

// LayerNorm per row (256 cols). grid = 2048 rows, 256 threads
__global__ __launch_bounds__(256) void ln_kernel(
    const float* __restrict__ in, float* __restrict__ outp,
    const float* __restrict__ g, const float* __restrict__ b)
{
  int row = blockIdx.x, t = threadIdx.x;
  float v = in[row * 256 + t];
  float s1 = wave_reduce_sum(v);
  float s2 = wave_reduce_sum(v * v);
  __shared__ float a1[4], a2[4];
  int w = t >> 6;
  if ((t & 63) == 0) { a1[w] = s1; a2[w] = s2; }
  __syncthreads();
  float ts1 = a1[0] + a1[1] + a1[2] + a1[3];
  float ts2 = a2[0] + a2[1] + a2[2] + a2[3];
  float mu = ts1 * (1.f / 256.f);
  float var = ts2 * (1.f / 256.f) - mu * mu;
  outp[row * 256 + t] = (v - mu) * rsqrtf(var + 1e-5f) * g[t] + b[t];
}

// QKV projections + phi + mask. grid (256 rowblocks, 3), 256 threads
__global__ __launch_bounds__(256) void qkv_kernel(
    const float* __restrict__ y, const float* __restrict__ counts,
    const float* __restrict__ Wq, const float* __restrict__ bq,
    const float* __restrict__ Wk, const float* __restrict__ bk,
    const float* __restrict__ Wv, const float* __restrict__ bv,
    float* __restrict__ qo, float* __restrict__ ko, float* __restrict__ vo)
{
  int m = blockIdx.y;
  const float* W = (m == 0) ? Wq : ((m == 1) ? Wk : Wv);
  const float* bias = (m == 0) ? bq : ((m == 1) ? bk : bv);
  float* outp = (m == 0) ? qo : ((m == 1) ? ko : vo);
  int rb = blockIdx.x, col = threadIdx.x;
  __shared__ float yl[8][256];
  for (int i = threadIdx.x; i < 8 * 256; i += 256)
    yl[i >> 8][i & 255] = y[(rb * 8 + (i >> 8)) * 256 + (i & 255)];
  __syncthreads();
  float acc[8] = {0, 0, 0, 0, 0, 0, 0, 0};
  #pragma unroll 4
  for (int kk = 0; kk < 256; kk++) {
    float wv = W[kk * 256 + col];
    #pragma unroll
    for (int r = 0; r < 8; r++) acc[r] += yl[r][kk] * wv;
  }
  #pragma unroll
  for (int r = 0; r < 8; r++) {
    int row = rb * 8 + r;
    float tv = acc[r] + bias[col];
    if (m <= 1) tv = (tv > 0.f) ? (tv + 1.f) : expf(tv);   // phi = elu+1
    if (m >= 1) tv *= (counts[row] > 0.f) ? 1.f : 0.f;     // mask on k,v
    outp[row * 256 + col] = tv;
  }
}

// kv[s,h,d,e] = sum_k k*v ; ksum[s,h,d]. grid S*NH*8 = 128 blocks
__global__ __launch_bounds__(256) void kv_kernel(
    const float* __restrict__ kw, const float* __restrict__ vw,
    float* __restrict__ kvb, float* __restrict__ ksb)
{
  int b = blockIdx.x, t = threadIdx.x;
  int s = b / (NH * 8), h = (b / 8) % NH, ck = b & 7;
  __shared__ float kl[64], vl[64];
  float acc[16];
  #pragma unroll
  for (int j = 0; j < 16; j++) acc[j] = 0.f;
  float acck = 0.f;
  int d = t & 63, eb = (t >> 6) * 16;
  for (int kk = ck * 64; kk < ck * 64 + 64; kk++) {
    if (t < 64) kl[t] = kw[((size_t)(s * KSEG + kk) * NH + h) * HD + t];
    else if (t < 128) vl[t - 64] = vw[((size_t)(s * KSEG + kk) * NH + h) * HD + (t - 64)];
    __syncthreads();
    float kd = kl[d];
    if (t < 64) acck += kd;
    #pragma unroll
    for (int j = 0; j < 16; j++) acc[j] += kd * vl[eb + j];
    __syncthreads();
  }
  #pragma unroll
  for (int j = 0; j < 16; j++)
    atomicAdd(&kvb[(((size_t)(s * NH + h)) * HD + d) * HD + eb + j], acc[j]);
  if (t < 64) atomicAdd(&ksb[(s * NH + h) * HD + t], acck);
}

// a = num/den per row. grid S*8 = 32 blocks
__global__ __launch_bounds__(256) void attn_kernel(
    const float* __restrict__ qw, const float* __restrict__ kvb,
    const float* __restrict__ ksb, float* __restrict__ aw)
{
  __shared__ float kvl[NH * HD * HD];  // 64KB
  __shared__ float ksl[NH * HD];
  __shared__ float ql[256];
  int t = threadIdx.x, b = blockIdx.x;
  int s = b >> 3, r0 = (b & 7) * 64;
  for (int i = t; i < NH * HD * HD; i += 256) kvl[i] = kvb[s * NH * HD * HD + i];
  for (int i = t; i < NH * HD; i += 256) ksl[i] = ksb[s * NH * HD + i];
  __syncthreads();
  int h = t >> 6, e = t & 63;
  for (int r = 0; r < 64; r++) {
    int row = s * KSEG + r0 + r;
    ql[t] = qw[row * 256 + t];
    __syncthreads();
    float den = 1e-6f, num = 0.f;
    #pragma unroll 16
    for (int d = 0; d < 64; d++) {
      float qd = ql[h * 64 + d];
      den += qd * ksl[h * 64 + d];
      num += qd * kvl[(h * 64 + d) * 64 + e];
    }
    aw[row * 256 + t] = num / den;
    __syncthreads();
  }
}

// x2 = x + a@Wo + bo. grid 256
__global__ __launch_bounds__(256) void oproj_kernel(
    const float* __restrict__ aw, const float* __restrict__ x,
    const float* __restrict__ Wo, const float* __restrict__ bo,
    float* __restrict__ x2)
{
  int rb = blockIdx.x, col = threadIdx.x;
  __shared__ float al[8][256];
  for (int i = threadIdx.x; i < 8 * 256; i += 256)
    al[i >> 8][i & 255] = aw[(rb * 8 + (i >> 8)) * 256 + (i & 255)];
  __syncthreads();
  float acc[8] = {0, 0, 0, 0, 0, 0, 0, 0};
  #pragma unroll 4
  for (int kk = 0; kk < 256; kk++) {
    float wv = Wo[kk * 256 + col];
    #pragma unroll
    for (int r = 0; r < 8; r++) acc[r] += al[r][kk] * wv;
  }
  #pragma unroll
  for (int r = 0; r < 8; r++) {
    int row = rb * 8 + r;
    x2[row * 256 + col] = x[row * 256 + col] + acc[r] + bo[col];
  }
}

// hid = gelu(y2 @ ffn_W1 + b1). grid (256, 4)
__global__ __launch_bounds__(256) void ffn1_kernel(
    const float* __restrict__ y2, const float* __restrict__ W1,
    const float* __restrict__ b1, float* __restrict__ hid)
{
  int rb = blockIdx.x, col = blockIdx.y * 256 + threadIdx.x;
  __shared__ float yl[8][256];
  for (int i = threadIdx.x; i < 8 * 256; i += 256)
    yl[i >> 8][i & 255] = y2[(rb * 8 + (i >> 8)) * 256 + (i & 255)];
  __syncthreads();
  float acc[8] = {0, 0, 0, 0, 0, 0, 0, 0};
  #pragma unroll 4
  for (int kk = 0; kk < 256; kk++) {
    float wv = W1[kk * FF + col];
    #pragma unroll
    for (int r = 0; r < 8; r++) acc[r] += yl[r][kk] * wv;
  }
  #pragma unroll
  for (int r = 0; r < 8; r++)
    hid[(size_t)(rb * 8 + r) * FF + col] = gelu_f(acc[r] + b1[col]);
}

// psu = x2 + hid @ ffn_W2 + b2 ; also psu_bf16. grid 256
__global__ __launch_bounds__(256) void ffn2_kernel(
    const float* __restrict__ hid, const float* __restrict__ x2,
    const float* __restrict__ W2, const float* __restrict__ b2,
    float* __restrict__ psu_out, unsigned short* __restrict__ psub)
{
  int rb = blockIdx.x, col = threadIdx.x;
  __shared__ float hl[8][FF];  // 32KB
  for (int i = threadIdx.x; i < 8 * FF; i += 256)
    hl[i >> 10][i & 1023] = hid[(size_t)(rb * 8 + (i >> 10)) * FF + (i & 1023)];
  __syncthreads();
  float acc[8] = {0, 0, 0, 0, 0, 0, 0, 0};
  #pragma unroll 4
  for (int kk = 0; kk < FF; kk++) {
    float wv = W2[kk * 256 + col];
    #pragma unroll
    for (int r = 0; r < 8; r++) acc[r] += hl[r][kk] * wv;
  }
  #pragma unroll
  for (int r = 0; r < 8; r++) {
    int row = rb * 8 + r;
    float tv = x2[row * 256 + col] + acc[r] + b2[col];
    psu_out[row * 256 + col] = tv;
    psub[row * 256 + col] = f2bf(tv);
  }
}

// Pre-transpose mlp weights to bf16 [col][k]. grid 768x256
__global__ __launch_bounds__(256) void wprep_kernel(
    const float* __restrict__ mW1, const float* __restrict__ mW2,
    unsigned short* __restrict__ W1t, unsigned short* __restrict__ W2t)
{
  int i = blockIdx.x * 256 + threadIdx.x;
  if (i < 131072) {
    int c = i >> 9, kk = i & 511;
    W1t[i] = f2bf(mW1[kk * 256 + c]);
  } else {
    int j = i - 131072;
    int c = j >> 8, kk = j & 255;
    W2t[j] = f2bf(mW2[kk * 256 + c]);
  }
}

// ---------------- Phase C: fused node MLP (bf16 MFMA) ----------------
// out = H + gelu([H, psu[pid]] @ mW1 + mb1) @ mW2 + mb2
// grid 2048 blocks (64 rows each), 256 threads (4 waves, 4x4 frags each)
#define AP 520   // A row stride (bf16): 512 + 8 pad
#define BP 40    // B col stride (bf16): 32 + 8 pad
#define HP 264   // hid row stride (bf16): 256 + 8 pad
__global__ __launch_bounds__(256) void node_mlp_kernel(
    const float* __restrict__ H, const int* __restrict__ pids,
    const unsigned short* __restrict__ psub,
    const unsigned short* __restrict__ W1t, const unsigned short* __restrict__ W2t,
    const float* __restrict__ b1, const float* __restrict__ b2,
    float* __restrict__ out)
{
  __shared__ unsigned short Albs[64 * AP];   // 66560 B
  __shared__ unsigned short Blds[256 * BP];  // 20480 B
  __shared__ unsigned short Hlds[64 * HP];   // 33792 B
  int tid = threadIdx.x;
  int lane = tid & 63, w = tid >> 6;
  int ln15 = lane & 15, hi = lane >> 4;
  int base = blockIdx.x * 64;

  // Stage A, H part (k = 0..255): fp32 -> bf16
  for (int i = tid; i < 64 * 64; i += 256) {
    int r = i >> 6, c4 = i & 63;
    float4 f = *(const float4*)(H + ((size_t)(base + r)) * 256 + c4 * 4);
    unsigned int lo = (unsigned int)f2bf(f.x) | ((unsigned int)f2bf(f.y) << 16);
    unsigned int hi2 = (unsigned int)f2bf(f.z) | ((unsigned int)f2bf(f.w) << 16);
    u32x2 val = {lo, hi2};
    *((u32x2*)&Albs[r * AP + c4 * 4]) = val;
  }
  // Stage A, bc part (k = 256..511): gather psu_bf16 rows
  for (int i = tid; i < 64 * 32; i += 256) {
    int r = i >> 5, ch = i & 31;
    int node = base + r;
    int ss = node >> 15;           // N = 2^15
    int nn = node & 32767;
    int pid = pids[ss * N + nn];
    const u32x4* src = (const u32x4*)(psub + ((size_t)(ss * KSEG + pid)) * 256 + ch * 8);
    *((u32x4*)&Albs[r * AP + 256 + ch * 8]) = *src;
  }

  f32x4 acc[4][4];
  #pragma unroll
  for (int a = 0; a < 4; a++)
    #pragma unroll
    for (int c = 0; c < 4; c++) acc[a][c] = (f32x4){0.f, 0.f, 0.f, 0.f};

  // ---- GEMM1: [64x512] @ [512x256] ----
  for (int kc = 0; kc < 16; kc++) {
    __syncthreads();  // A visible (kc=0) / prior B reads done (kc>0)
    for (int i = tid; i < 256 * 4; i += 256) {
      int c = i >> 2, k8 = i & 3;
      *((u32x4*)&Blds[c * BP + k8 * 8]) =
          *(const u32x4*)(W1t + (size_t)c * 512 + kc * 32 + k8 * 8);
    }
    __syncthreads();
    short8 a[4], b[4];
    #pragma unroll
    for (int rt = 0; rt < 4; rt++)
      a[rt] = *(const short8*)(&Albs[(rt * 16 + ln15) * AP + kc * 32 + hi * 8]);
    #pragma unroll
    for (int ct = 0; ct < 4; ct++)
      b[ct] = *(const short8*)(&Blds[(w * 64 + ct * 16 + ln15) * BP + hi * 8]);
    #pragma unroll
    for (int rt = 0; rt < 4; rt++)
      #pragma unroll
      for (int ct = 0; ct < 4; ct++)
        acc[rt][ct] = __builtin_amdgcn_mfma_f32_16x16x32_bf16(a[rt], b[ct], acc[rt][ct], 0, 0, 0);
  }

  // epilogue 1: bias + gelu -> Hlds (bf16)
  #pragma unroll
  for (int rt = 0; rt < 4; rt++) {
    #pragma unroll
    for (int ct = 0; ct < 4; ct++) {
      int col = w * 64 + ct * 16 + ln15;
      float bb = b1[col];
      #pragma unroll
      for (int r = 0; r < 4; r++) {
        int row = rt * 16 + hi * 4 + r;
        float tv = acc[rt][ct][r] + bb;
        Hlds[row * HP + col] = f2bf(gelu_f(tv));
      }
      acc[rt][ct] = (f32x4){0.f, 0.f, 0.f, 0.f};
    }
  }
  __syncthreads();  // Hid visible to all waves; GEMM1 B reads done

  // ---- GEMM2: [64x256] @ [256x256] ----
  for (int kc = 0; kc < 8; kc++) {
    if (kc) __syncthreads();
    for (int i = tid; i < 256 * 4; i += 256) {
      int c = i >> 2, k8 = i & 3;
      *((u32x4*)&Blds[c * BP + k8 * 8]) =
          *(const u32x4*)(W2t + (size_t)c * 256 + kc * 32 + k8 * 8);
    }
    __syncthreads();
    short8 a[4], b[4];
    #pragma unroll
    for (int rt = 0; rt < 4; rt++)
      a[rt] = *(const short8*)(&Hlds[(rt * 16 + ln15) * HP + kc * 32 + hi * 8]);
    #pragma unroll
    for (int ct = 0; ct < 4; ct++)
      b[ct] = *(const short8*)(&Blds[(w * 64 + ct * 16 + ln15) * BP + hi * 8]);
    #pragma unroll
    for (int rt = 0; rt < 4; rt++)
      #pragma unroll
      for (int ct = 0; ct < 4; ct++)
        acc[rt][ct] = __builtin_amdgcn_mfma_f32_16x16x32_bf16(a[rt], b[ct], acc[rt][ct], 0, 0, 0);
  }

  // final epilogue: out = H + acc + b2
  #pragma unroll
  for (int rt = 0; rt < 4; rt++) {
    #pragma unroll
    for (int ct = 0; ct < 4; ct++) {
      int col = w * 64 + ct * 16 + ln15;
      float bb = b2[col];
      #pragma unroll
      for (int r = 0; r < 4; r++) {
        size_t idx = ((size_t)(base + rt * 16 + hi * 4 + r)) * 256 + col;
        out[idx] = H[idx] + acc[rt][ct][r] + bb;
      }
    }
  }
}

extern "C" void kernel_launch(void* const* d_in, const int* in_sizes, int n_in,
                              void* d_out, int out_size, void* d_ws, size_t ws_size,
                              hipStream_t stream) {
  (void)in_sizes; (void)n_in; (void)out_size; (void)ws_size;
  const float* H    = (const float*)d_in[0];
  const int*   pids = (const int*)d_in[1];
  const float* ln1g = (const float*)d_in[2];
  const float* ln1b = (const float*)d_in[3];
  const float* Wq   = (const float*)d_in[4];
  const float* bq   = (const float*)d_in[5];
  const float* Wk   = (const float*)d_in[6];
  const float* bk   = (const float*)d_in[7];
  const float* Wv   = (const float*)d_in[8];
  const float* bv   = (const float*)d_in[9];
  const float* Wo   = (const float*)d_in[10];
  const float* bo   = (const float*)d_in[11];
  const float* ln2g = (const float*)d_in[12];
  const float* ln2b = (const float*)d_in[13];
  const float* fW1  = (const float*)d_in[14];
  const float* fb1  = (const float*)d_in[15];
  const float* fW2  = (const float*)d_in[16];
  const float* fb2  = (const float*)d_in[17];
  const float* mW1  = (const float*)d_in[18];
  const float* mb1  = (const float*)d_in[19];
  const float* mW2  = (const float*)d_in[20];
  const float* mb2  = (const float*)d_in[21];
  float* out = (float*)d_out;
  float* ws = (float*)d_ws;

  float* sums   = ws;                  // 524288
  float* counts = ws + 524288;         // 2048
  float* xw     = ws + 526336;         // 524288
  float* yw     = ws + 1050624;        // 524288
  float* qw     = ws + 1574912;        // 524288
  float* kw     = ws + 2099200;        // 524288
  float* vw     = ws + 2623488;        // 524288
  float* kvb    = ws + 3147776;        // 65536
  float* ksb    = ws + 3213312;        // 1024
  float* aw     = ws + 3214336;        // 524288
  float* x2w    = ws + 3738624;        // 524288
  float* y2w    = ws + 4262912;        // 524288
  float* hidw   = ws + 4787200;        // 2097152
  unsigned short* psub = (unsigned short*)(ws + 6884352);  // 524288 bf16
  unsigned short* W1t  = (unsigned short*)(ws + 7146496);  // 131072 bf16
  unsigned short* W2t  = (unsigned short*)(ws + 7212032);  // 65536 bf16

  hipMemsetAsync(sums, 0, (524288 + 2048) * sizeof(float), stream);
  hipMemsetAsync(kvb, 0, (65536 + 1024) * sizeof(float), stream);

  wprep_kernel<<<768, 256, 0, stream>>>(mW1, mW2, W1t, W2t);
  pool_kernel<<<256, 256, 0, stream>>>(H, pids, sums, counts);
  finalize_kernel<<<2048, 256, 0, stream>>>(sums, counts, xw);
  ln_kernel<<<2048, 256, 0, stream>>>(xw, yw, ln1g, ln1b);
  qkv_kernel<<<dim3(256, 3), 256, 0, stream>>>(yw, counts, Wq, bq, Wk, bk, Wv, bv, qw, kw, vw);
  kv_kernel<<<128, 256, 0, stream>>>(kw, vw, kvb, ksb);
  attn_kernel<<<32, 256, 0, stream>>>(qw, kvb, ksb, aw);
  oproj_kernel<<<256, 256, 0, stream>>>(aw, xw, Wo, bo, x2w);
  ln_kernel<<<2048, 256, 0, stream>>>(x2w, y2w, ln2g, ln2b);
  ffn1_kernel<<<dim3(256, 4), 256, 0, stream>>>(y2w, fW1, fb1, hidw);
  ffn2_kernel<<<256, 256, 0, stream>>>(hidw, x2w, fW2, fb2, out + (size_t)S * N * D, psub);
  node_mlp_kernel<<<2048, 256, 0, stream>>>(H, pids, psub, W1t, W2t, mb1, mb2, out);
}

// Round 2
// 615.447 us; speedup vs baseline: 1.3746x; 1.3746x over previous
//
#include <hip/hip_runtime.h>
#include <hip/hip_bf16.h>

#define S 4
#define N 32768
#define D 256
#define KSEG 512
#define NH 4
#define HD 64
#define FF 1024

typedef __attribute__((ext_vector_type(8))) short short8;
typedef __attribute__((ext_vector_type(4))) float f32x4;
typedef __attribute__((ext_vector_type(4))) unsigned int u32x4;
typedef __attribute__((ext_vector_type(2))) unsigned int u32x2;

__device__ __forceinline__ unsigned short f2bf(float f) {
  union { __hip_bfloat16 h; unsigned short u; } cv;
  cv.h = __float2bfloat16(f);
  return cv.u;
}

__device__ __forceinline__ float gelu_f(float x) {
  return 0.5f * x * (1.0f + erff(x * 0.70710678118654752440f));
}

__device__ __forceinline__ float wave_reduce_sum(float v) {
  #pragma unroll
  for (int o = 32; o > 0; o >>= 1) v += __shfl_xor(v, o, 64);
  return v;
}

// ---------------- Phase A: segment-mean pooling ----------------
#define NCHUNK 8
__global__ __launch_bounds__(256) void pool_kernel(
    const float* __restrict__ H, const int* __restrict__ pids,
    float* __restrict__ sums, float* __restrict__ counts)
{
  __shared__ float acc[KSEG * 32];  // 64KB
  __shared__ float cnt[KSEG];
  int t = threadIdx.x;
  int b = blockIdx.x;
  int chunk = b & 7, ds = (b >> 3) & 7, s = b >> 6;
  for (int i = t; i < KSEG * 32; i += 256) acc[i] = 0.f;
  if (ds == 0) for (int i = t; i < KSEG; i += 256) cnt[i] = 0.f;
  __syncthreads();
  int d0 = ds * 32;
  int dlane = t & 31, nsub = t >> 5;
  int n0 = chunk * (N / NCHUNK);
  for (int i = 0; i < N / NCHUNK; i += 32) {
    int pid[4]; float h[4];
    #pragma unroll
    for (int u = 0; u < 4; u++) {
      int n = n0 + i + u * 8 + nsub;
      pid[u] = pids[s * N + n];
      h[u] = H[((size_t)(s * N + n)) * D + d0 + dlane];
    }
    #pragma unroll
    for (int u = 0; u < 4; u++) {
      atomicAdd(&acc[pid[u] * 32 + dlane], h[u]);
      if (ds == 0 && dlane == 0) atomicAdd(&cnt[pid[u]], 1.f);
    }
  }
  __syncthreads();
  for (int i = t; i < KSEG * 32; i += 256) {
    float v = acc[i];
    if (v != 0.f) atomicAdd(&sums[((size_t)(s * KSEG + (i >> 5))) * D + d0 + (i & 31)], v);
  }
  if (ds == 0) {
    for (int i = t; i < KSEG; i += 256) {
      float c = cnt[i];
      if (c != 0.f) atomicAdd(&counts[s * KSEG + i], c);
    }
  }
}

// x = sums/max(c,1); y = LN(x). grid 2048 rows
__global__ __launch_bounds__(256) void pool_ln_kernel(
    const float* __restrict__ sums, const float* __restrict__ counts,
    const float* __restrict__ g, const float* __restrict__ b,
    float* __restrict__ xw, float* __restrict__ yw)
{
  int row = blockIdx.x, t = threadIdx.x;
  float c = counts[row];
  float v = sums[row * 256 + t] / fmaxf(c, 1.f);
  xw[row * 256 + t] = v;
  float s1 = wave_reduce_sum(v);
  float s2 = wave_reduce_sum(v * v);
  __shared__ float a1[4], a2[4];
  int w = t >> 6;
  if ((t & 63) == 0) { a1[w] = s1; a2[w] = s2; }
  __syncthreads();
  float ts1 = a1[0] + a1[1] + a1[2] + a1[3];
  float ts2 = a2[0] + a2[1] + a2[2] + a2[3];
  float mu = ts1 * (1.f / 256.f);
  float var = ts2 * (1.f / 256.f) - mu * mu;
  yw[row * 256 + t] = (v - mu) * rsqrtf(var + 1e-5f) * g[t] + b[t];
}

// LayerNorm per row. grid 2048 rows
__global__ __launch_bounds__(256) void ln_kernel(
    const float* __restrict__ in, float* __restrict__ outp,
    const float* __restrict__ g, const float* __restrict__ b)
{
  int row = blockIdx.x, t = threadIdx.x;
  float v = in[row * 256 + t];
  float s1 = wave_reduce_sum(v);
  float s2 = wave_reduce_sum(v * v);
  __shared__ float a1[4], a2[4];
  int w = t >> 6;
  if ((t & 63) == 0) { a1[w] = s1; a2[w] = s2; }
  __syncthreads();
  float ts1 = a1[0] + a1[1] + a1[2] + a1[3];
  float ts2 = a2[0] + a2[1] + a2[2] + a2[3];
  float mu = ts1 * (1.f / 256.f);
  float var = ts2 * (1.f / 256.f) - mu * mu;
  outp[row * 256 + t] = (v - mu) * rsqrtf(var + 1e-5f) * g[t] + b[t];
}

// QKV projections + phi + mask. grid (256, 3)
__global__ __launch_bounds__(256) void qkv_kernel(
    const float* __restrict__ y, const float* __restrict__ counts,
    const float* __restrict__ Wq, const float* __restrict__ bq,
    const float* __restrict__ Wk, const float* __restrict__ bk,
    const float* __restrict__ Wv, const float* __restrict__ bv,
    float* __restrict__ qo, float* __restrict__ ko, float* __restrict__ vo)
{
  int m = blockIdx.y;
  const float* W = (m == 0) ? Wq : ((m == 1) ? Wk : Wv);
  const float* bias = (m == 0) ? bq : ((m == 1) ? bk : bv);
  float* outp = (m == 0) ? qo : ((m == 1) ? ko : vo);
  int rb = blockIdx.x, col = threadIdx.x;
  __shared__ float yl[8][256];
  for (int i = threadIdx.x; i < 8 * 256; i += 256)
    yl[i >> 8][i & 255] = y[(rb * 8 + (i >> 8)) * 256 + (i & 255)];
  __syncthreads();
  float acc[8] = {0, 0, 0, 0, 0, 0, 0, 0};
  #pragma unroll 4
  for (int kk = 0; kk < 256; kk++) {
    float wv = W[kk * 256 + col];
    #pragma unroll
    for (int r = 0; r < 8; r++) acc[r] += yl[r][kk] * wv;
  }
  #pragma unroll
  for (int r = 0; r < 8; r++) {
    int row = rb * 8 + r;
    float tv = acc[r] + bias[col];
    if (m <= 1) tv = (tv > 0.f) ? (tv + 1.f) : expf(tv);   // phi = elu+1
    if (m >= 1) tv *= (counts[row] > 0.f) ? 1.f : 0.f;     // mask on k,v
    outp[row * 256 + col] = tv;
  }
}

// kv[s,h,d,e] = sum_k k*v ; ksum[s,h,d]. grid 128 blocks
__global__ __launch_bounds__(256) void kv_kernel(
    const float* __restrict__ kw, const float* __restrict__ vw,
    float* __restrict__ kvb, float* __restrict__ ksb)
{
  int b = blockIdx.x, t = threadIdx.x;
  int s = b / (NH * 8), h = (b / 8) % NH, ck = b & 7;
  __shared__ float kl[64], vl[64];
  float acc[16];
  #pragma unroll
  for (int j = 0; j < 16; j++) acc[j] = 0.f;
  float acck = 0.f;
  int d = t & 63, eb = (t >> 6) * 16;
  for (int kk = ck * 64; kk < ck * 64 + 64; kk++) {
    if (t < 64) kl[t] = kw[((size_t)(s * KSEG + kk) * NH + h) * HD + t];
    else if (t < 128) vl[t - 64] = vw[((size_t)(s * KSEG + kk) * NH + h) * HD + (t - 64)];
    __syncthreads();
    float kd = kl[d];
    if (t < 64) acck += kd;
    #pragma unroll
    for (int j = 0; j < 16; j++) acc[j] += kd * vl[eb + j];
    __syncthreads();
  }
  #pragma unroll
  for (int j = 0; j < 16; j++)
    atomicAdd(&kvb[(((size_t)(s * NH + h)) * HD + d) * HD + eb + j], acc[j]);
  if (t < 64) atomicAdd(&ksb[(s * NH + h) * HD + t], acck);
}

// a = num/den per row, register-tiled. grid 256 blocks = 16 (s,h) x 16 rowblocks
__global__ __launch_bounds__(256) void attn_kernel(
    const float* __restrict__ qw, const float* __restrict__ kvb,
    const float* __restrict__ ksb, float* __restrict__ aw)
{
  __shared__ float kvl[64 * 64];   // 16 KB  kvl[d*64+e]
  __shared__ float ksl[64];
  __shared__ float ql[32 * 64];    // 8 KB   ql[r*64+d]
  int t = threadIdx.x, b = blockIdx.x;
  int sh = b >> 4, rb = b & 15;
  int s = sh >> 2, h = sh & 3;
  for (int i = t; i < 4096; i += 256) kvl[i] = kvb[sh * 4096 + i];
  if (t < 64) ksl[t] = ksb[sh * 64 + t];
  for (int i = t; i < 2048; i += 256) {
    int r = i >> 6, d = i & 63;
    ql[i] = qw[((size_t)(s * KSEG + rb * 32 + r)) * 256 + h * 64 + d];
  }
  __syncthreads();
  int e = t & 63, rg = t >> 6;
  float num[8], den[8];
  #pragma unroll
  for (int r = 0; r < 8; r++) { num[r] = 0.f; den[r] = 0.f; }
  #pragma unroll 4
  for (int d4 = 0; d4 < 64; d4 += 4) {
    float4 ks4 = *(const float4*)&ksl[d4];
    float kv0 = kvl[(d4 + 0) * 64 + e];
    float kv1 = kvl[(d4 + 1) * 64 + e];
    float kv2 = kvl[(d4 + 2) * 64 + e];
    float kv3 = kvl[(d4 + 3) * 64 + e];
    #pragma unroll
    for (int r = 0; r < 8; r++) {
      float4 q4 = *(const float4*)&ql[(rg * 8 + r) * 64 + d4];
      num[r] += q4.x * kv0 + q4.y * kv1 + q4.z * kv2 + q4.w * kv3;
      den[r] += q4.x * ks4.x + q4.y * ks4.y + q4.z * ks4.z + q4.w * ks4.w;
    }
  }
  #pragma unroll
  for (int r = 0; r < 8; r++) {
    int row = rb * 32 + rg * 8 + r;
    aw[((size_t)(s * KSEG + row)) * 256 + h * 64 + e] = num[r] / (den[r] + 1e-6f);
  }
}

// x2 = x + a@Wo + bo. grid 256
__global__ __launch_bounds__(256) void oproj_kernel(
    const float* __restrict__ aw, const float* __restrict__ x,
    const float* __restrict__ Wo, const float* __restrict__ bo,
    float* __restrict__ x2)
{
  int rb = blockIdx.x, col = threadIdx.x;
  __shared__ float al[8][256];
  for (int i = threadIdx.x; i < 8 * 256; i += 256)
    al[i >> 8][i & 255] = aw[(rb * 8 + (i >> 8)) * 256 + (i & 255)];
  __syncthreads();
  float acc[8] = {0, 0, 0, 0, 0, 0, 0, 0};
  #pragma unroll 4
  for (int kk = 0; kk < 256; kk++) {
    float wv = Wo[kk * 256 + col];
    #pragma unroll
    for (int r = 0; r < 8; r++) acc[r] += al[r][kk] * wv;
  }
  #pragma unroll
  for (int r = 0; r < 8; r++) {
    int row = rb * 8 + r;
    x2[row * 256 + col] = x[row * 256 + col] + acc[r] + bo[col];
  }
}

// hid = gelu(y2 @ ffn_W1 + b1). grid (256, 4)
__global__ __launch_bounds__(256) void ffn1_kernel(
    const float* __restrict__ y2, const float* __restrict__ W1,
    const float* __restrict__ b1, float* __restrict__ hid)
{
  int rb = blockIdx.x, col = blockIdx.y * 256 + threadIdx.x;
  __shared__ float yl[8][256];
  for (int i = threadIdx.x; i < 8 * 256; i += 256)
    yl[i >> 8][i & 255] = y2[(rb * 8 + (i >> 8)) * 256 + (i & 255)];
  __syncthreads();
  float acc[8] = {0, 0, 0, 0, 0, 0, 0, 0};
  #pragma unroll 4
  for (int kk = 0; kk < 256; kk++) {
    float wv = W1[kk * FF + col];
    #pragma unroll
    for (int r = 0; r < 8; r++) acc[r] += yl[r][kk] * wv;
  }
  #pragma unroll
  for (int r = 0; r < 8; r++)
    hid[(size_t)(rb * 8 + r) * FF + col] = gelu_f(acc[r] + b1[col]);
}

// psu = x2 + hid @ ffn_W2 + b2 ; also psu_bf16. grid 256
__global__ __launch_bounds__(256) void ffn2_kernel(
    const float* __restrict__ hid, const float* __restrict__ x2,
    const float* __restrict__ W2, const float* __restrict__ b2,
    float* __restrict__ psu_out, unsigned short* __restrict__ psub)
{
  int rb = blockIdx.x, col = threadIdx.x;
  __shared__ float hl[8][FF];  // 32KB
  for (int i = threadIdx.x; i < 8 * FF; i += 256)
    hl[i >> 10][i & 1023] = hid[(size_t)(rb * 8 + (i >> 10)) * FF + (i & 1023)];
  __syncthreads();
  float acc[8] = {0, 0, 0, 0, 0, 0, 0, 0};
  #pragma unroll 4
  for (int kk = 0; kk < FF; kk++) {
    float wv = W2[kk * 256 + col];
    #pragma unroll
    for (int r = 0; r < 8; r++) acc[r] += hl[r][kk] * wv;
  }
  #pragma unroll
  for (int r = 0; r < 8; r++) {
    int row = rb * 8 + r;
    float tv = x2[row * 256 + col] + acc[r] + b2[col];
    psu_out[row * 256 + col] = tv;
    psub[row * 256 + col] = f2bf(tv);
  }
}

// Pre-pack mlp weights to bf16 in MFMA-fragment order.
// W1f: tile = (col>>4)*16 + kc (kc<16), 512 shorts/tile: [lane][j] =
//      W1[(kc*32 + (lane>>4)*8 + j)*256 + (col16*16 + (lane&15))]
// W2f: tile = (col>>4)*8 + kc (kc<8), same inner layout.
__global__ __launch_bounds__(256) void wprep_kernel(
    const float* __restrict__ mW1, const float* __restrict__ mW2,
    unsigned short* __restrict__ W1f, unsigned short* __restrict__ W2f)
{
  int i = blockIdx.x * 256 + threadIdx.x;
  if (i < 131072) {
    int tile = i >> 9, idx = i & 511;
    int lane = idx >> 3, j = idx & 7;
    int c = tile >> 4, kc = tile & 15;
    int k = kc * 32 + (lane >> 4) * 8 + j;
    int col = c * 16 + (lane & 15);
    W1f[i] = f2bf(mW1[k * 256 + col]);
  } else {
    int i2 = i - 131072;
    int tile = i2 >> 9, idx = i2 & 511;
    int lane = idx >> 3, j = idx & 7;
    int c = tile >> 3, kc = tile & 7;
    int k = kc * 32 + (lane >> 4) * 8 + j;
    int col = c * 16 + (lane & 15);
    W2f[i2] = f2bf(mW2[k * 256 + col]);
  }
}

// ---------------- Phase C: fused node MLP (bf16 MFMA) ----------------
// out = H + gelu([H, psu[pid]] @ mW1 + mb1) @ mW2 + mb2
// grid 2048 blocks (64 rows), 256 threads (4 waves x 4x4 frags).
// LDS 66560 B (2 blocks/CU), aliased A-tile / Hid-tile / C-tile.
// B fragments streamed from L2 (fragment-packed W1f/W2f), no K-loop barriers.
#define AP 520   // A row stride (bf16): 512 + 8 pad  (row stride == 4 banks)
#define HP 264   // hid row stride (bf16): 256 + 8 pad
#define CP 260   // C row stride (f32): 256 + 4 pad
__global__ __launch_bounds__(256, 2) void node_mlp_kernel(
    const float* __restrict__ H, const int* __restrict__ pids,
    const unsigned short* __restrict__ psub,
    const unsigned short* __restrict__ W1f, const unsigned short* __restrict__ W2f,
    const float* __restrict__ b1, const float* __restrict__ b2,
    float* __restrict__ out)
{
  __shared__ __align__(16) unsigned char smem[64 * AP * 2];  // 66560 B
  unsigned short* Albs = (unsigned short*)smem;   // A: 64 x AP bf16
  unsigned short* Hlds = (unsigned short*)smem;   // Hid: 64 x HP bf16 (alias)
  float* Cl = (float*)smem;                       // C: 64 x CP f32 (alias)
  int tid = threadIdx.x;
  int lane = tid & 63, w = tid >> 6;
  int ln15 = lane & 15, hi = lane >> 4;
  int base = blockIdx.x * 64;

  // Stage A, H part (k = 0..255): fp32 -> bf16, coalesced
  for (int i = tid; i < 64 * 64; i += 256) {
    int r = i >> 6, c4 = i & 63;
    float4 f = *(const float4*)(H + ((size_t)(base + r)) * 256 + c4 * 4);
    unsigned int lo = (unsigned int)f2bf(f.x) | ((unsigned int)f2bf(f.y) << 16);
    unsigned int hi2 = (unsigned int)f2bf(f.z) | ((unsigned int)f2bf(f.w) << 16);
    u32x2 val = {lo, hi2};
    *((u32x2*)&Albs[r * AP + c4 * 4]) = val;
  }
  // Stage A, bc part (k = 256..511): gather psu_bf16 rows
  for (int i = tid; i < 64 * 32; i += 256) {
    int r = i >> 5, ch = i & 31;
    int node = base + r;
    int ss = node >> 15, nn = node & 32767;
    int pid = pids[ss * N + nn];
    *((u32x4*)&Albs[r * AP + 256 + ch * 8]) =
        *(const u32x4*)(psub + ((size_t)(ss * KSEG + pid)) * 256 + ch * 8);
  }
  __syncthreads();

  f32x4 acc[4][4];
  #pragma unroll
  for (int a = 0; a < 4; a++)
    #pragma unroll
    for (int c = 0; c < 4; c++) acc[a][c] = (f32x4){0.f, 0.f, 0.f, 0.f};

  // ---- GEMM1: [64x512] @ [512x256], B streamed from L2 ----
  {
    const unsigned short* Wl = W1f + (size_t)lane * 8;
    short8 bcur[4];
    #pragma unroll
    for (int ct = 0; ct < 4; ct++)
      bcur[ct] = *(const short8*)(Wl + ((w * 4 + ct) * 16 + 0) * 512);
    #pragma unroll
    for (int kc = 0; kc < 16; kc++) {
      short8 a[4], bnext[4];
      #pragma unroll
      for (int rt = 0; rt < 4; rt++)
        a[rt] = *(const short8*)(&Albs[(rt * 16 + ln15) * AP + kc * 32 + hi * 8]);
      if (kc < 15) {
        #pragma unroll
        for (int ct = 0; ct < 4; ct++)
          bnext[ct] = *(const short8*)(Wl + ((w * 4 + ct) * 16 + kc + 1) * 512);
      }
      #pragma unroll
      for (int rt = 0; rt < 4; rt++)
        #pragma unroll
        for (int ct = 0; ct < 4; ct++)
          acc[rt][ct] = __builtin_amdgcn_mfma_f32_16x16x32_bf16(a[rt], bcur[ct], acc[rt][ct], 0, 0, 0);
      if (kc < 15) {
        #pragma unroll
        for (int ct = 0; ct < 4; ct++) bcur[ct] = bnext[ct];
      }
    }
  }

  __syncthreads();  // all A reads done; safe to overwrite with Hid

  // epilogue 1: bias + gelu -> Hid (bf16, aliased over A)
  #pragma unroll
  for (int rt = 0; rt < 4; rt++) {
    #pragma unroll
    for (int ct = 0; ct < 4; ct++) {
      int col = w * 64 + ct * 16 + ln15;
      float bb = b1[col];
      #pragma unroll
      for (int r = 0; r < 4; r++) {
        int row = rt * 16 + hi * 4 + r;
        Hlds[row * HP + col] = f2bf(gelu_f(acc[rt][ct][r] + bb));
      }
      acc[rt][ct] = (f32x4){0.f, 0.f, 0.f, 0.f};
    }
  }
  __syncthreads();  // Hid visible

  // ---- GEMM2: [64x256] @ [256x256], B streamed from L2 ----
  {
    const unsigned short* Wl = W2f + (size_t)lane * 8;
    short8 bcur[4];
    #pragma unroll
    for (int ct = 0; ct < 4; ct++)
      bcur[ct] = *(const short8*)(Wl + ((w * 4 + ct) * 8 + 0) * 512);
    #pragma unroll
    for (int kc = 0; kc < 8; kc++) {
      short8 a[4], bnext[4];
      #pragma unroll
      for (int rt = 0; rt < 4; rt++)
        a[rt] = *(const short8*)(&Hlds[(rt * 16 + ln15) * HP + kc * 32 + hi * 8]);
      if (kc < 7) {
        #pragma unroll
        for (int ct = 0; ct < 4; ct++)
          bnext[ct] = *(const short8*)(Wl + ((w * 4 + ct) * 8 + kc + 1) * 512);
      }
      #pragma unroll
      for (int rt = 0; rt < 4; rt++)
        #pragma unroll
        for (int ct = 0; ct < 4; ct++)
          acc[rt][ct] = __builtin_amdgcn_mfma_f32_16x16x32_bf16(a[rt], bcur[ct], acc[rt][ct], 0, 0, 0);
      if (kc < 7) {
        #pragma unroll
        for (int ct = 0; ct < 4; ct++) bcur[ct] = bnext[ct];
      }
    }
  }

  __syncthreads();  // all Hid reads done; safe to overwrite with C

  // stage C (+bias) to LDS for coalesced writeback
  #pragma unroll
  for (int rt = 0; rt < 4; rt++) {
    #pragma unroll
    for (int ct = 0; ct < 4; ct++) {
      int col = w * 64 + ct * 16 + ln15;
      float bb = b2[col];
      #pragma unroll
      for (int r = 0; r < 4; r++)
        Cl[(rt * 16 + hi * 4 + r) * CP + col] = acc[rt][ct][r] + bb;
    }
  }
  __syncthreads();

  // out = H + C, fully coalesced float4
  for (int i = tid; i < 64 * 64; i += 256) {
    int r = i >> 6, c4 = i & 63;
    size_t gidx = ((size_t)(base + r)) * 256 + c4 * 4;
    float4 h4 = *(const float4*)(H + gidx);
    float4 cv = *(const float4*)&Cl[r * CP + c4 * 4];
    float4 o4 = {h4.x + cv.x, h4.y + cv.y, h4.z + cv.z, h4.w + cv.w};
    *(float4*)(out + gidx) = o4;
  }
}

extern "C" void kernel_launch(void* const* d_in, const int* in_sizes, int n_in,
                              void* d_out, int out_size, void* d_ws, size_t ws_size,
                              hipStream_t stream) {
  (void)in_sizes; (void)n_in; (void)out_size; (void)ws_size;
  const float* H    = (const float*)d_in[0];
  const int*   pids = (const int*)d_in[1];
  const float* ln1g = (const float*)d_in[2];
  const float* ln1b = (const float*)d_in[3];
  const float* Wq   = (const float*)d_in[4];
  const float* bq   = (const float*)d_in[5];
  const float* Wk   = (const float*)d_in[6];
  const float* bk   = (const float*)d_in[7];
  const float* Wv   = (const float*)d_in[8];
  const float* bv   = (const float*)d_in[9];
  const float* Wo   = (const float*)d_in[10];
  const float* bo   = (const float*)d_in[11];
  const float* ln2g = (const float*)d_in[12];
  const float* ln2b = (const float*)d_in[13];
  const float* fW1  = (const float*)d_in[14];
  const float* fb1  = (const float*)d_in[15];
  const float* fW2  = (const float*)d_in[16];
  const float* fb2  = (const float*)d_in[17];
  const float* mW1  = (const float*)d_in[18];
  const float* mb1  = (const float*)d_in[19];
  const float* mW2  = (const float*)d_in[20];
  const float* mb2  = (const float*)d_in[21];
  float* out = (float*)d_out;
  float* ws = (float*)d_ws;

  float* sums   = ws;                  // 524288
  float* counts = ws + 524288;         // 2048
  float* xw     = ws + 526336;         // 524288
  float* yw     = ws + 1050624;        // 524288
  float* qw     = ws + 1574912;        // 524288
  float* kw     = ws + 2099200;        // 524288
  float* vw     = ws + 2623488;        // 524288
  float* kvb    = ws + 3147776;        // 65536
  float* ksb    = ws + 3213312;        // 1024
  float* aw     = ws + 3214336;        // 524288
  float* x2w    = ws + 3738624;        // 524288
  float* y2w    = ws + 4262912;        // 524288
  float* hidw   = ws + 4787200;        // 2097152
  unsigned short* psub = (unsigned short*)(ws + 6884352);  // 524288 bf16
  unsigned short* W1f  = (unsigned short*)(ws + 7146496);  // 131072 bf16
  unsigned short* W2f  = (unsigned short*)(ws + 7212032);  // 65536 bf16

  hipMemsetAsync(sums, 0, (524288 + 2048) * sizeof(float), stream);
  hipMemsetAsync(kvb, 0, (65536 + 1024) * sizeof(float), stream);

  wprep_kernel<<<768, 256, 0, stream>>>(mW1, mW2, W1f, W2f);
  pool_kernel<<<256, 256, 0, stream>>>(H, pids, sums, counts);
  pool_ln_kernel<<<2048, 256, 0, stream>>>(sums, counts, ln1g, ln1b, xw, yw);
  qkv_kernel<<<dim3(256, 3), 256, 0, stream>>>(yw, counts, Wq, bq, Wk, bk, Wv, bv, qw, kw, vw);
  kv_kernel<<<128, 256, 0, stream>>>(kw, vw, kvb, ksb);
  attn_kernel<<<256, 256, 0, stream>>>(qw, kvb, ksb, aw);
  oproj_kernel<<<256, 256, 0, stream>>>(aw, xw, Wo, bo, x2w);
  ln_kernel<<<2048, 256, 0, stream>>>(x2w, y2w, ln2g, ln2b);
  ffn1_kernel<<<dim3(256, 4), 256, 0, stream>>>(y2w, fW1, fb1, hidw);
  ffn2_kernel<<<256, 256, 0, stream>>>(hidw, x2w, fW2, fb2, out + (size_t)S * N * D, psub);
  node_mlp_kernel<<<2048, 256, 0, stream>>>(H, pids, psub, W1f, W2f, mb1, mb2, out);
}

// Round 3
// 563.911 us; speedup vs baseline: 1.5003x; 1.0914x over previous
//
#include <hip/hip_runtime.h>
#include <hip/hip_bf16.h>

#define S 4
#define N 32768
#define D 256
#define KSEG 512
#define NH 4
#define HD 64
#define FF 1024

typedef __attribute__((ext_vector_type(8))) short short8;
typedef __attribute__((ext_vector_type(4))) float f32x4;
typedef __attribute__((ext_vector_type(4))) unsigned int u32x4;
typedef __attribute__((ext_vector_type(2))) unsigned int u32x2;

__device__ __forceinline__ unsigned short f2bf(float f) {
  union { __hip_bfloat16 h; unsigned short u; } cv;
  cv.h = __float2bfloat16(f);
  return cv.u;
}

__device__ __forceinline__ float gelu_f(float x) {
  return 0.5f * x * (1.0f + erff(x * 0.70710678118654752440f));
}

__device__ __forceinline__ float wave_reduce_sum(float v) {
  #pragma unroll
  for (int o = 32; o > 0; o >>= 1) v += __shfl_xor(v, o, 64);
  return v;
}

// ---------------- Phase A: counts histogram ----------------
// grid 64 blocks = 4 s x 16 chunks
__global__ __launch_bounds__(256) void counts_kernel(
    const int* __restrict__ pids, float* __restrict__ counts)
{
  __shared__ int hist[KSEG];
  int b = blockIdx.x, t = threadIdx.x;
  int s = b >> 4, chunk = b & 15;
  for (int i = t; i < KSEG; i += 256) hist[i] = 0;
  __syncthreads();
  const int* p = pids + s * N + chunk * 2048;
  for (int i = t; i < 2048; i += 256) atomicAdd(&hist[p[i]], 1);
  __syncthreads();
  for (int i = t; i < KSEG; i += 256)
    if (hist[i]) atomicAdd(&counts[s * KSEG + i], (float)hist[i]);
}

// ---------------- Phase A: segment-sum pooling ----------------
// grid 1024 blocks = 4 s x 16 dslices(16 dims) x 16 chunks(2048 nodes)
// LDS ~37KB -> 4 blocks/CU, 16 waves/CU. 8-deep load batching.
__global__ __launch_bounds__(256, 4) void pool_kernel(
    const float* __restrict__ H, const int* __restrict__ pids,
    float* __restrict__ sums)
{
  __shared__ float acc[KSEG * 16];        // 32 KB
  __shared__ unsigned short pl[2048];     // 4 KB
  int t = threadIdx.x, b = blockIdx.x;
  int chunk = b & 15, ds = (b >> 4) & 15, s = b >> 8;
  for (int i = t; i < KSEG * 16; i += 256) acc[i] = 0.f;
  const int* p = pids + s * N + chunk * 2048;
  for (int i = t; i < 2048; i += 256) pl[i] = (unsigned short)p[i];
  __syncthreads();
  int d0 = ds * 16, dlane = t & 15, nsub = t >> 4;  // nsub 0..15
  size_t hbase = ((size_t)s * N + chunk * 2048) * 256 + d0 + dlane;
  for (int it = 0; it < 16; it++) {
    int nb = it * 128 + nsub;
    int pid[8]; float h[8];
    #pragma unroll
    for (int u = 0; u < 8; u++) {
      pid[u] = pl[nb + u * 16];
      h[u] = H[hbase + (size_t)(nb + u * 16) * 256];
    }
    #pragma unroll
    for (int u = 0; u < 8; u++)
      atomicAdd(&acc[pid[u] * 16 + dlane], h[u]);
  }
  __syncthreads();
  for (int i = t; i < KSEG * 16; i += 256) {
    float v = acc[i];
    if (v != 0.f)
      atomicAdd(&sums[((size_t)(s * KSEG + (i >> 4))) * 256 + d0 + (i & 15)], v);
  }
}

// x = sums/max(c,1); y = LN(x). grid 2048 rows
__global__ __launch_bounds__(256) void pool_ln_kernel(
    const float* __restrict__ sums, const float* __restrict__ counts,
    const float* __restrict__ g, const float* __restrict__ b,
    float* __restrict__ xw, float* __restrict__ yw)
{
  int row = blockIdx.x, t = threadIdx.x;
  float c = counts[row];
  float v = sums[row * 256 + t] / fmaxf(c, 1.f);
  xw[row * 256 + t] = v;
  float s1 = wave_reduce_sum(v);
  float s2 = wave_reduce_sum(v * v);
  __shared__ float a1[4], a2[4];
  int w = t >> 6;
  if ((t & 63) == 0) { a1[w] = s1; a2[w] = s2; }
  __syncthreads();
  float ts1 = a1[0] + a1[1] + a1[2] + a1[3];
  float ts2 = a2[0] + a2[1] + a2[2] + a2[3];
  float mu = ts1 * (1.f / 256.f);
  float var = ts2 * (1.f / 256.f) - mu * mu;
  yw[row * 256 + t] = (v - mu) * rsqrtf(var + 1e-5f) * g[t] + b[t];
}

// LayerNorm per row. grid 2048 rows
__global__ __launch_bounds__(256) void ln_kernel(
    const float* __restrict__ in, float* __restrict__ outp,
    const float* __restrict__ g, const float* __restrict__ b)
{
  int row = blockIdx.x, t = threadIdx.x;
  float v = in[row * 256 + t];
  float s1 = wave_reduce_sum(v);
  float s2 = wave_reduce_sum(v * v);
  __shared__ float a1[4], a2[4];
  int w = t >> 6;
  if ((t & 63) == 0) { a1[w] = s1; a2[w] = s2; }
  __syncthreads();
  float ts1 = a1[0] + a1[1] + a1[2] + a1[3];
  float ts2 = a2[0] + a2[1] + a2[2] + a2[3];
  float mu = ts1 * (1.f / 256.f);
  float var = ts2 * (1.f / 256.f) - mu * mu;
  outp[row * 256 + t] = (v - mu) * rsqrtf(var + 1e-5f) * g[t] + b[t];
}

// QKV projections + phi + mask. grid (256, 3)
__global__ __launch_bounds__(256) void qkv_kernel(
    const float* __restrict__ y, const float* __restrict__ counts,
    const float* __restrict__ Wq, const float* __restrict__ bq,
    const float* __restrict__ Wk, const float* __restrict__ bk,
    const float* __restrict__ Wv, const float* __restrict__ bv,
    float* __restrict__ qo, float* __restrict__ ko, float* __restrict__ vo)
{
  int m = blockIdx.y;
  const float* W = (m == 0) ? Wq : ((m == 1) ? Wk : Wv);
  const float* bias = (m == 0) ? bq : ((m == 1) ? bk : bv);
  float* outp = (m == 0) ? qo : ((m == 1) ? ko : vo);
  int rb = blockIdx.x, col = threadIdx.x;
  __shared__ float yl[8][256];
  for (int i = threadIdx.x; i < 8 * 256; i += 256)
    yl[i >> 8][i & 255] = y[(rb * 8 + (i >> 8)) * 256 + (i & 255)];
  __syncthreads();
  float acc[8] = {0, 0, 0, 0, 0, 0, 0, 0};
  #pragma unroll 4
  for (int kk = 0; kk < 256; kk++) {
    float wv = W[kk * 256 + col];
    #pragma unroll
    for (int r = 0; r < 8; r++) acc[r] += yl[r][kk] * wv;
  }
  #pragma unroll
  for (int r = 0; r < 8; r++) {
    int row = rb * 8 + r;
    float tv = acc[r] + bias[col];
    if (m <= 1) tv = (tv > 0.f) ? (tv + 1.f) : expf(tv);   // phi = elu+1
    if (m >= 1) tv *= (counts[row] > 0.f) ? 1.f : 0.f;     // mask on k,v
    outp[row * 256 + col] = tv;
  }
}

// kv[s,h,d,e] = sum_k k*v ; ksum[s,h,d]. grid 128 blocks
__global__ __launch_bounds__(256) void kv_kernel(
    const float* __restrict__ kw, const float* __restrict__ vw,
    float* __restrict__ kvb, float* __restrict__ ksb)
{
  int b = blockIdx.x, t = threadIdx.x;
  int s = b / (NH * 8), h = (b / 8) % NH, ck = b & 7;
  __shared__ float kl[64], vl[64];
  float acc[16];
  #pragma unroll
  for (int j = 0; j < 16; j++) acc[j] = 0.f;
  float acck = 0.f;
  int d = t & 63, eb = (t >> 6) * 16;
  for (int kk = ck * 64; kk < ck * 64 + 64; kk++) {
    if (t < 64) kl[t] = kw[((size_t)(s * KSEG + kk) * NH + h) * HD + t];
    else if (t < 128) vl[t - 64] = vw[((size_t)(s * KSEG + kk) * NH + h) * HD + (t - 64)];
    __syncthreads();
    float kd = kl[d];
    if (t < 64) acck += kd;
    #pragma unroll
    for (int j = 0; j < 16; j++) acc[j] += kd * vl[eb + j];
    __syncthreads();
  }
  #pragma unroll
  for (int j = 0; j < 16; j++)
    atomicAdd(&kvb[(((size_t)(s * NH + h)) * HD + d) * HD + eb + j], acc[j]);
  if (t < 64) atomicAdd(&ksb[(s * NH + h) * HD + t], acck);
}

// a = num/den per row, register-tiled. grid 256 blocks
__global__ __launch_bounds__(256) void attn_kernel(
    const float* __restrict__ qw, const float* __restrict__ kvb,
    const float* __restrict__ ksb, float* __restrict__ aw)
{
  __shared__ float kvl[64 * 64];   // 16 KB
  __shared__ float ksl[64];
  __shared__ float ql[32 * 64];    // 8 KB
  int t = threadIdx.x, b = blockIdx.x;
  int sh = b >> 4, rb = b & 15;
  int s = sh >> 2, h = sh & 3;
  for (int i = t; i < 4096; i += 256) kvl[i] = kvb[sh * 4096 + i];
  if (t < 64) ksl[t] = ksb[sh * 64 + t];
  for (int i = t; i < 2048; i += 256) {
    int r = i >> 6, d = i & 63;
    ql[i] = qw[((size_t)(s * KSEG + rb * 32 + r)) * 256 + h * 64 + d];
  }
  __syncthreads();
  int e = t & 63, rg = t >> 6;
  float num[8], den[8];
  #pragma unroll
  for (int r = 0; r < 8; r++) { num[r] = 0.f; den[r] = 0.f; }
  #pragma unroll 4
  for (int d4 = 0; d4 < 64; d4 += 4) {
    float4 ks4 = *(const float4*)&ksl[d4];
    float kv0 = kvl[(d4 + 0) * 64 + e];
    float kv1 = kvl[(d4 + 1) * 64 + e];
    float kv2 = kvl[(d4 + 2) * 64 + e];
    float kv3 = kvl[(d4 + 3) * 64 + e];
    #pragma unroll
    for (int r = 0; r < 8; r++) {
      float4 q4 = *(const float4*)&ql[(rg * 8 + r) * 64 + d4];
      num[r] += q4.x * kv0 + q4.y * kv1 + q4.z * kv2 + q4.w * kv3;
      den[r] += q4.x * ks4.x + q4.y * ks4.y + q4.z * ks4.z + q4.w * ks4.w;
    }
  }
  #pragma unroll
  for (int r = 0; r < 8; r++) {
    int row = rb * 32 + rg * 8 + r;
    aw[((size_t)(s * KSEG + row)) * 256 + h * 64 + e] = num[r] / (den[r] + 1e-6f);
  }
}

// x2 = x + a@Wo + bo. grid 256
__global__ __launch_bounds__(256) void oproj_kernel(
    const float* __restrict__ aw, const float* __restrict__ x,
    const float* __restrict__ Wo, const float* __restrict__ bo,
    float* __restrict__ x2)
{
  int rb = blockIdx.x, col = threadIdx.x;
  __shared__ float al[8][256];
  for (int i = threadIdx.x; i < 8 * 256; i += 256)
    al[i >> 8][i & 255] = aw[(rb * 8 + (i >> 8)) * 256 + (i & 255)];
  __syncthreads();
  float acc[8] = {0, 0, 0, 0, 0, 0, 0, 0};
  #pragma unroll 4
  for (int kk = 0; kk < 256; kk++) {
    float wv = Wo[kk * 256 + col];
    #pragma unroll
    for (int r = 0; r < 8; r++) acc[r] += al[r][kk] * wv;
  }
  #pragma unroll
  for (int r = 0; r < 8; r++) {
    int row = rb * 8 + r;
    x2[row * 256 + col] = x[row * 256 + col] + acc[r] + bo[col];
  }
}

// hid = gelu(y2 @ ffn_W1 + b1). grid (256, 4)
__global__ __launch_bounds__(256) void ffn1_kernel(
    const float* __restrict__ y2, const float* __restrict__ W1,
    const float* __restrict__ b1, float* __restrict__ hid)
{
  int rb = blockIdx.x, col = blockIdx.y * 256 + threadIdx.x;
  __shared__ float yl[8][256];
  for (int i = threadIdx.x; i < 8 * 256; i += 256)
    yl[i >> 8][i & 255] = y2[(rb * 8 + (i >> 8)) * 256 + (i & 255)];
  __syncthreads();
  float acc[8] = {0, 0, 0, 0, 0, 0, 0, 0};
  #pragma unroll 4
  for (int kk = 0; kk < 256; kk++) {
    float wv = W1[kk * FF + col];
    #pragma unroll
    for (int r = 0; r < 8; r++) acc[r] += yl[r][kk] * wv;
  }
  #pragma unroll
  for (int r = 0; r < 8; r++)
    hid[(size_t)(rb * 8 + r) * FF + col] = gelu_f(acc[r] + b1[col]);
}

// psu = x2 + hid @ ffn_W2 + b2 ; also psu_bf16. grid 256
__global__ __launch_bounds__(256) void ffn2_kernel(
    const float* __restrict__ hid, const float* __restrict__ x2,
    const float* __restrict__ W2, const float* __restrict__ b2,
    float* __restrict__ psu_out, unsigned short* __restrict__ psub)
{
  int rb = blockIdx.x, col = threadIdx.x;
  __shared__ float hl[8][FF];  // 32KB
  for (int i = threadIdx.x; i < 8 * FF; i += 256)
    hl[i >> 10][i & 1023] = hid[(size_t)(rb * 8 + (i >> 10)) * FF + (i & 1023)];
  __syncthreads();
  float acc[8] = {0, 0, 0, 0, 0, 0, 0, 0};
  #pragma unroll 4
  for (int kk = 0; kk < FF; kk++) {
    float wv = W2[kk * 256 + col];
    #pragma unroll
    for (int r = 0; r < 8; r++) acc[r] += hl[r][kk] * wv;
  }
  #pragma unroll
  for (int r = 0; r < 8; r++) {
    int row = rb * 8 + r;
    float tv = x2[row * 256 + col] + acc[r] + b2[col];
    psu_out[row * 256 + col] = tv;
    psub[row * 256 + col] = f2bf(tv);
  }
}

// Pre-pack mlp weights to bf16 in MFMA-fragment order.
__global__ __launch_bounds__(256) void wprep_kernel(
    const float* __restrict__ mW1, const float* __restrict__ mW2,
    unsigned short* __restrict__ W1f, unsigned short* __restrict__ W2f)
{
  int i = blockIdx.x * 256 + threadIdx.x;
  if (i < 131072) {
    int tile = i >> 9, idx = i & 511;
    int lane = idx >> 3, j = idx & 7;
    int c = tile >> 4, kc = tile & 15;
    int k = kc * 32 + (lane >> 4) * 8 + j;
    int col = c * 16 + (lane & 15);
    W1f[i] = f2bf(mW1[k * 256 + col]);
  } else {
    int i2 = i - 131072;
    int tile = i2 >> 9, idx = i2 & 511;
    int lane = idx >> 3, j = idx & 7;
    int c = tile >> 3, kc = tile & 7;
    int k = kc * 32 + (lane >> 4) * 8 + j;
    int col = c * 16 + (lane & 15);
    W2f[i2] = f2bf(mW2[k * 256 + col]);
  }
}

// ---------------- Phase C: fused node MLP (bf16 MFMA) ----------------
#define AP 520   // A row stride (bf16): 512 + 8 pad
#define HP 264   // hid row stride (bf16): 256 + 8 pad
#define CP 260   // C row stride (f32): 256 + 4 pad
__global__ __launch_bounds__(256, 2) void node_mlp_kernel(
    const float* __restrict__ H, const int* __restrict__ pids,
    const unsigned short* __restrict__ psub,
    const unsigned short* __restrict__ W1f, const unsigned short* __restrict__ W2f,
    const float* __restrict__ b1, const float* __restrict__ b2,
    float* __restrict__ out)
{
  __shared__ __align__(16) unsigned char smem[64 * AP * 2];  // 66560 B
  unsigned short* Albs = (unsigned short*)smem;
  unsigned short* Hlds = (unsigned short*)smem;
  float* Cl = (float*)smem;
  int tid = threadIdx.x;
  int lane = tid & 63, w = tid >> 6;
  int ln15 = lane & 15, hi = lane >> 4;
  int base = blockIdx.x * 64;

  for (int i = tid; i < 64 * 64; i += 256) {
    int r = i >> 6, c4 = i & 63;
    float4 f = *(const float4*)(H + ((size_t)(base + r)) * 256 + c4 * 4);
    unsigned int lo = (unsigned int)f2bf(f.x) | ((unsigned int)f2bf(f.y) << 16);
    unsigned int hi2 = (unsigned int)f2bf(f.z) | ((unsigned int)f2bf(f.w) << 16);
    u32x2 val = {lo, hi2};
    *((u32x2*)&Albs[r * AP + c4 * 4]) = val;
  }
  for (int i = tid; i < 64 * 32; i += 256) {
    int r = i >> 5, ch = i & 31;
    int node = base + r;
    int ss = node >> 15, nn = node & 32767;
    int pid = pids[ss * N + nn];
    *((u32x4*)&Albs[r * AP + 256 + ch * 8]) =
        *(const u32x4*)(psub + ((size_t)(ss * KSEG + pid)) * 256 + ch * 8);
  }
  __syncthreads();

  f32x4 acc[4][4];
  #pragma unroll
  for (int a = 0; a < 4; a++)
    #pragma unroll
    for (int c = 0; c < 4; c++) acc[a][c] = (f32x4){0.f, 0.f, 0.f, 0.f};

  // ---- GEMM1: [64x512] @ [512x256], B streamed from L2 ----
  {
    const unsigned short* Wl = W1f + (size_t)lane * 8;
    short8 bcur[4];
    #pragma unroll
    for (int ct = 0; ct < 4; ct++)
      bcur[ct] = *(const short8*)(Wl + ((w * 4 + ct) * 16 + 0) * 512);
    #pragma unroll
    for (int kc = 0; kc < 16; kc++) {
      short8 a[4], bnext[4];
      #pragma unroll
      for (int rt = 0; rt < 4; rt++)
        a[rt] = *(const short8*)(&Albs[(rt * 16 + ln15) * AP + kc * 32 + hi * 8]);
      if (kc < 15) {
        #pragma unroll
        for (int ct = 0; ct < 4; ct++)
          bnext[ct] = *(const short8*)(Wl + ((w * 4 + ct) * 16 + kc + 1) * 512);
      }
      #pragma unroll
      for (int rt = 0; rt < 4; rt++)
        #pragma unroll
        for (int ct = 0; ct < 4; ct++)
          acc[rt][ct] = __builtin_amdgcn_mfma_f32_16x16x32_bf16(a[rt], bcur[ct], acc[rt][ct], 0, 0, 0);
      if (kc < 15) {
        #pragma unroll
        for (int ct = 0; ct < 4; ct++) bcur[ct] = bnext[ct];
      }
    }
  }

  __syncthreads();

  #pragma unroll
  for (int rt = 0; rt < 4; rt++) {
    #pragma unroll
    for (int ct = 0; ct < 4; ct++) {
      int col = w * 64 + ct * 16 + ln15;
      float bb = b1[col];
      #pragma unroll
      for (int r = 0; r < 4; r++) {
        int row = rt * 16 + hi * 4 + r;
        Hlds[row * HP + col] = f2bf(gelu_f(acc[rt][ct][r] + bb));
      }
      acc[rt][ct] = (f32x4){0.f, 0.f, 0.f, 0.f};
    }
  }
  __syncthreads();

  // ---- GEMM2: [64x256] @ [256x256], B streamed from L2 ----
  {
    const unsigned short* Wl = W2f + (size_t)lane * 8;
    short8 bcur[4];
    #pragma unroll
    for (int ct = 0; ct < 4; ct++)
      bcur[ct] = *(const short8*)(Wl + ((w * 4 + ct) * 8 + 0) * 512);
    #pragma unroll
    for (int kc = 0; kc < 8; kc++) {
      short8 a[4], bnext[4];
      #pragma unroll
      for (int rt = 0; rt < 4; rt++)
        a[rt] = *(const short8*)(&Hlds[(rt * 16 + ln15) * HP + kc * 32 + hi * 8]);
      if (kc < 7) {
        #pragma unroll
        for (int ct = 0; ct < 4; ct++)
          bnext[ct] = *(const short8*)(Wl + ((w * 4 + ct) * 8 + kc + 1) * 512);
      }
      #pragma unroll
      for (int rt = 0; rt < 4; rt++)
        #pragma unroll
        for (int ct = 0; ct < 4; ct++)
          acc[rt][ct] = __builtin_amdgcn_mfma_f32_16x16x32_bf16(a[rt], bcur[ct], acc[rt][ct], 0, 0, 0);
      if (kc < 7) {
        #pragma unroll
        for (int ct = 0; ct < 4; ct++) bcur[ct] = bnext[ct];
      }
    }
  }

  __syncthreads();

  #pragma unroll
  for (int rt = 0; rt < 4; rt++) {
    #pragma unroll
    for (int ct = 0; ct < 4; ct++) {
      int col = w * 64 + ct * 16 + ln15;
      float bb = b2[col];
      #pragma unroll
      for (int r = 0; r < 4; r++)
        Cl[(rt * 16 + hi * 4 + r) * CP + col] = acc[rt][ct][r] + bb;
    }
  }
  __syncthreads();

  for (int i = tid; i < 64 * 64; i += 256) {
    int r = i >> 6, c4 = i & 63;
    size_t gidx = ((size_t)(base + r)) * 256 + c4 * 4;
    float4 h4 = *(const float4*)(H + gidx);
    float4 cv = *(const float4*)&Cl[r * CP + c4 * 4];
    float4 o4 = {h4.x + cv.x, h4.y + cv.y, h4.z + cv.z, h4.w + cv.w};
    *(float4*)(out + gidx) = o4;
  }
}

extern "C" void kernel_launch(void* const* d_in, const int* in_sizes, int n_in,
                              void* d_out, int out_size, void* d_ws, size_t ws_size,
                              hipStream_t stream) {
  (void)in_sizes; (void)n_in; (void)out_size; (void)ws_size;
  const float* H    = (const float*)d_in[0];
  const int*   pids = (const int*)d_in[1];
  const float* ln1g = (const float*)d_in[2];
  const float* ln1b = (const float*)d_in[3];
  const float* Wq   = (const float*)d_in[4];
  const float* bq   = (const float*)d_in[5];
  const float* Wk   = (const float*)d_in[6];
  const float* bk   = (const float*)d_in[7];
  const float* Wv   = (const float*)d_in[8];
  const float* bv   = (const float*)d_in[9];
  const float* Wo   = (const float*)d_in[10];
  const float* bo   = (const float*)d_in[11];
  const float* ln2g = (const float*)d_in[12];
  const float* ln2b = (const float*)d_in[13];
  const float* fW1  = (const float*)d_in[14];
  const float* fb1  = (const float*)d_in[15];
  const float* fW2  = (const float*)d_in[16];
  const float* fb2  = (const float*)d_in[17];
  const float* mW1  = (const float*)d_in[18];
  const float* mb1  = (const float*)d_in[19];
  const float* mW2  = (const float*)d_in[20];
  const float* mb2  = (const float*)d_in[21];
  float* out = (float*)d_out;
  float* ws = (float*)d_ws;

  float* sums   = ws;                  // 524288
  float* counts = ws + 524288;         // 2048
  float* xw     = ws + 526336;         // 524288
  float* yw     = ws + 1050624;        // 524288
  float* qw     = ws + 1574912;        // 524288
  float* kw     = ws + 2099200;        // 524288
  float* vw     = ws + 2623488;        // 524288
  float* kvb    = ws + 3147776;        // 65536
  float* ksb    = ws + 3213312;        // 1024
  float* aw     = ws + 3214336;        // 524288
  float* x2w    = ws + 3738624;        // 524288
  float* y2w    = ws + 4262912;        // 524288
  float* hidw   = ws + 4787200;        // 2097152
  unsigned short* psub = (unsigned short*)(ws + 6884352);  // 524288 bf16
  unsigned short* W1f  = (unsigned short*)(ws + 7146496);  // 131072 bf16
  unsigned short* W2f  = (unsigned short*)(ws + 7212032);  // 65536 bf16

  hipMemsetAsync(sums, 0, (524288 + 2048) * sizeof(float), stream);
  hipMemsetAsync(kvb, 0, (65536 + 1024) * sizeof(float), stream);

  wprep_kernel<<<768, 256, 0, stream>>>(mW1, mW2, W1f, W2f);
  counts_kernel<<<64, 256, 0, stream>>>(pids, counts);
  pool_kernel<<<1024, 256, 0, stream>>>(H, pids, sums);
  pool_ln_kernel<<<2048, 256, 0, stream>>>(sums, counts, ln1g, ln1b, xw, yw);
  qkv_kernel<<<dim3(256, 3), 256, 0, stream>>>(yw, counts, Wq, bq, Wk, bk, Wv, bv, qw, kw, vw);
  kv_kernel<<<128, 256, 0, stream>>>(kw, vw, kvb, ksb);
  attn_kernel<<<256, 256, 0, stream>>>(qw, kvb, ksb, aw);
  oproj_kernel<<<256, 256, 0, stream>>>(aw, xw, Wo, bo, x2w);
  ln_kernel<<<2048, 256, 0, stream>>>(x2w, y2w, ln2g, ln2b);
  ffn1_kernel<<<dim3(256, 4), 256, 0, stream>>>(y2w, fW1, fb1, hidw);
  ffn2_kernel<<<256, 256, 0, stream>>>(hidw, x2w, fW2, fb2, out + (size_t)S * N * D, psub);
  node_mlp_kernel<<<2048, 256, 0, stream>>>(H, pids, psub, W1f, W2f, mb1, mb2, out);
}

// Round 4
// 447.210 us; speedup vs baseline: 1.8918x; 1.2610x over previous
//
#include <hip/hip_runtime.h>
#include <hip/hip_bf16.h>

#define S 4
#define N 32768
#define D 256
#define KSEG 512
#define NH 4
#define HD 64
#define FF 1024

typedef __attribute__((ext_vector_type(8))) short short8;
typedef __attribute__((ext_vector_type(4))) float f32x4;
typedef __attribute__((ext_vector_type(4))) unsigned int u32x4;
typedef __attribute__((ext_vector_type(2))) unsigned int u32x2;

__device__ __forceinline__ unsigned short f2bf(float f) {
  union { __hip_bfloat16 h; unsigned short u; } cv;
  cv.h = __float2bfloat16(f);
  return cv.u;
}

__device__ __forceinline__ float gelu_f(float x) {
  return 0.5f * x * (1.0f + erff(x * 0.70710678118654752440f));
}

__device__ __forceinline__ float wave_reduce_sum(float v) {
  #pragma unroll
  for (int o = 32; o > 0; o >>= 1) v += __shfl_xor(v, o, 64);
  return v;
}

// ---------------- Phase A: counting sort by patch id ----------------
// 1) per-(s,chunk) histogram. grid 64 = 4 s x 16 chunks
__global__ __launch_bounds__(256) void hist_kernel(
    const int* __restrict__ pids, int* __restrict__ histc)
{
  __shared__ int h[KSEG];
  int b = blockIdx.x, t = threadIdx.x;
  int s = b >> 4, c = b & 15;
  for (int i = t; i < KSEG; i += 256) h[i] = 0;
  __syncthreads();
  const int* p = pids + s * N + c * 2048;
  for (int i = t; i < 2048; i += 256) atomicAdd(&h[p[i]], 1);
  __syncthreads();
  for (int i = t; i < KSEG; i += 256) histc[(s * 16 + c) * KSEG + i] = h[i];
}

// 2) per-sample: counts, exclusive bin scan, per-chunk bases (in-place into histc).
// grid 4 (one per s), 256 threads
__global__ __launch_bounds__(256) void prefix_kernel(
    int* __restrict__ histc, int* __restrict__ segstart,
    int* __restrict__ cnti, float* __restrict__ counts)
{
  __shared__ int h[16 * KSEG];   // 32 KB
  __shared__ int sc[KSEG];       // bin counts
  __shared__ int sa[KSEG], sb[KSEG];
  int s = blockIdx.x, t = threadIdx.x;
  for (int i = t; i < 16 * KSEG; i += 256) h[i] = histc[s * 16 * KSEG + i];
  __syncthreads();
  #pragma unroll
  for (int u = 0; u < 2; u++) {
    int bin = t + u * 256;
    int cc = 0;
    #pragma unroll
    for (int c = 0; c < 16; c++) cc += h[c * KSEG + bin];
    sc[bin] = cc;
    sa[bin] = cc;
  }
  __syncthreads();
  // Hillis-Steele inclusive scan over 512 bins
  int* src = sa; int* dst = sb;
  for (int off = 1; off < KSEG; off <<= 1) {
    #pragma unroll
    for (int u = 0; u < 2; u++) {
      int bin = t + u * 256;
      int v = src[bin];
      if (bin >= off) v += src[bin - off];
      dst[bin] = v;
    }
    __syncthreads();
    int* tmp = src; src = dst; dst = tmp;
  }
  #pragma unroll
  for (int u = 0; u < 2; u++) {
    int bin = t + u * 256;
    int cc = sc[bin];
    int excl = src[bin] - cc;
    segstart[s * KSEG + bin] = excl;
    cnti[s * KSEG + bin] = cc;
    counts[s * KSEG + bin] = (float)cc;
    int run = excl;
    #pragma unroll
    for (int c = 0; c < 16; c++) {
      int v = h[c * KSEG + bin];
      h[c * KSEG + bin] = run;
      run += v;
    }
  }
  __syncthreads();
  for (int i = t; i < 16 * KSEG; i += 256) histc[s * 16 * KSEG + i] = h[i];
}

// 3) scatter node rows into segment-sorted order. grid 64 = 4 s x 16 chunks
__global__ __launch_bounds__(256) void scatter_kernel(
    const int* __restrict__ pids, const int* __restrict__ histc,
    int* __restrict__ order)
{
  __shared__ int offs[KSEG];
  int b = blockIdx.x, t = threadIdx.x;
  int s = b >> 4, c = b & 15;
  for (int i = t; i < KSEG; i += 256) offs[i] = histc[(s * 16 + c) * KSEG + i];
  __syncthreads();
  const int* p = pids + s * N + c * 2048;
  for (int i = t; i < 2048; i += 256) {
    int pid = p[i];
    int pos = atomicAdd(&offs[pid], 1);
    order[s * N + pos] = s * N + c * 2048 + i;  // absolute H row
  }
}

// 4) gather-reduce: one wave per segment, coalesced float4 row streams.
// grid 512 blocks x 256 threads (4 waves)
__global__ __launch_bounds__(256) void pool_gather(
    const float* __restrict__ H, const int* __restrict__ order,
    const int* __restrict__ segstart, const int* __restrict__ cnti,
    float* __restrict__ xw)
{
  int tid = threadIdx.x;
  int w = tid >> 6, lane = tid & 63;
  int seg = blockIdx.x * 4 + w;          // 0..2047
  int s = seg >> 9;
  int st = segstart[seg], cn = cnti[seg];
  int en = st + cn;
  const int* ord = order + (size_t)s * N;
  int c4 = lane << 2;
  f32x4 a0 = {0,0,0,0}, a1 = {0,0,0,0}, a2 = {0,0,0,0}, a3 = {0,0,0,0};
  f32x4 a4 = {0,0,0,0}, a5 = {0,0,0,0}, a6 = {0,0,0,0}, a7 = {0,0,0,0};
  int i = st;
  for (; i + 8 <= en; i += 8) {
    int r0 = ord[i + 0], r1 = ord[i + 1], r2 = ord[i + 2], r3 = ord[i + 3];
    int r4 = ord[i + 4], r5 = ord[i + 5], r6 = ord[i + 6], r7 = ord[i + 7];
    a0 += *(const f32x4*)(H + (size_t)r0 * 256 + c4);
    a1 += *(const f32x4*)(H + (size_t)r1 * 256 + c4);
    a2 += *(const f32x4*)(H + (size_t)r2 * 256 + c4);
    a3 += *(const f32x4*)(H + (size_t)r3 * 256 + c4);
    a4 += *(const f32x4*)(H + (size_t)r4 * 256 + c4);
    a5 += *(const f32x4*)(H + (size_t)r5 * 256 + c4);
    a6 += *(const f32x4*)(H + (size_t)r6 * 256 + c4);
    a7 += *(const f32x4*)(H + (size_t)r7 * 256 + c4);
  }
  for (; i < en; i++) {
    int r = ord[i];
    a0 += *(const f32x4*)(H + (size_t)r * 256 + c4);
  }
  f32x4 ssum = ((a0 + a1) + (a2 + a3)) + ((a4 + a5) + (a6 + a7));
  float inv = 1.f / fmaxf((float)cn, 1.f);
  ssum = ssum * inv;
  *(f32x4*)(xw + (size_t)seg * 256 + c4) = ssum;
}

// y = LN(x). grid 2048 rows
__global__ __launch_bounds__(256) void pool_ln_kernel(
    const float* __restrict__ xw,
    const float* __restrict__ g, const float* __restrict__ b,
    float* __restrict__ yw)
{
  int row = blockIdx.x, t = threadIdx.x;
  float v = xw[row * 256 + t];
  float s1 = wave_reduce_sum(v);
  float s2 = wave_reduce_sum(v * v);
  __shared__ float a1[4], a2[4];
  int w = t >> 6;
  if ((t & 63) == 0) { a1[w] = s1; a2[w] = s2; }
  __syncthreads();
  float ts1 = a1[0] + a1[1] + a1[2] + a1[3];
  float ts2 = a2[0] + a2[1] + a2[2] + a2[3];
  float mu = ts1 * (1.f / 256.f);
  float var = ts2 * (1.f / 256.f) - mu * mu;
  yw[row * 256 + t] = (v - mu) * rsqrtf(var + 1e-5f) * g[t] + b[t];
}

// LayerNorm per row. grid 2048 rows
__global__ __launch_bounds__(256) void ln_kernel(
    const float* __restrict__ in, float* __restrict__ outp,
    const float* __restrict__ g, const float* __restrict__ b)
{
  int row = blockIdx.x, t = threadIdx.x;
  float v = in[row * 256 + t];
  float s1 = wave_reduce_sum(v);
  float s2 = wave_reduce_sum(v * v);
  __shared__ float a1[4], a2[4];
  int w = t >> 6;
  if ((t & 63) == 0) { a1[w] = s1; a2[w] = s2; }
  __syncthreads();
  float ts1 = a1[0] + a1[1] + a1[2] + a1[3];
  float ts2 = a2[0] + a2[1] + a2[2] + a2[3];
  float mu = ts1 * (1.f / 256.f);
  float var = ts2 * (1.f / 256.f) - mu * mu;
  outp[row * 256 + t] = (v - mu) * rsqrtf(var + 1e-5f) * g[t] + b[t];
}

// QKV projections + phi + mask. grid (256, 3)
__global__ __launch_bounds__(256) void qkv_kernel(
    const float* __restrict__ y, const float* __restrict__ counts,
    const float* __restrict__ Wq, const float* __restrict__ bq,
    const float* __restrict__ Wk, const float* __restrict__ bk,
    const float* __restrict__ Wv, const float* __restrict__ bv,
    float* __restrict__ qo, float* __restrict__ ko, float* __restrict__ vo)
{
  int m = blockIdx.y;
  const float* W = (m == 0) ? Wq : ((m == 1) ? Wk : Wv);
  const float* bias = (m == 0) ? bq : ((m == 1) ? bk : bv);
  float* outp = (m == 0) ? qo : ((m == 1) ? ko : vo);
  int rb = blockIdx.x, col = threadIdx.x;
  __shared__ float yl[8][256];
  for (int i = threadIdx.x; i < 8 * 256; i += 256)
    yl[i >> 8][i & 255] = y[(rb * 8 + (i >> 8)) * 256 + (i & 255)];
  __syncthreads();
  float acc[8] = {0, 0, 0, 0, 0, 0, 0, 0};
  #pragma unroll 4
  for (int kk = 0; kk < 256; kk++) {
    float wv = W[kk * 256 + col];
    #pragma unroll
    for (int r = 0; r < 8; r++) acc[r] += yl[r][kk] * wv;
  }
  #pragma unroll
  for (int r = 0; r < 8; r++) {
    int row = rb * 8 + r;
    float tv = acc[r] + bias[col];
    if (m <= 1) tv = (tv > 0.f) ? (tv + 1.f) : expf(tv);   // phi = elu+1
    if (m >= 1) tv *= (counts[row] > 0.f) ? 1.f : 0.f;     // mask on k,v
    outp[row * 256 + col] = tv;
  }
}

// kv[s,h,d,e] = sum_k k*v ; ksum[s,h,d]. grid 128 blocks
__global__ __launch_bounds__(256) void kv_kernel(
    const float* __restrict__ kw, const float* __restrict__ vw,
    float* __restrict__ kvb, float* __restrict__ ksb)
{
  int b = blockIdx.x, t = threadIdx.x;
  int s = b / (NH * 8), h = (b / 8) % NH, ck = b & 7;
  __shared__ float kl[64], vl[64];
  float acc[16];
  #pragma unroll
  for (int j = 0; j < 16; j++) acc[j] = 0.f;
  float acck = 0.f;
  int d = t & 63, eb = (t >> 6) * 16;
  for (int kk = ck * 64; kk < ck * 64 + 64; kk++) {
    if (t < 64) kl[t] = kw[((size_t)(s * KSEG + kk) * NH + h) * HD + t];
    else if (t < 128) vl[t - 64] = vw[((size_t)(s * KSEG + kk) * NH + h) * HD + (t - 64)];
    __syncthreads();
    float kd = kl[d];
    if (t < 64) acck += kd;
    #pragma unroll
    for (int j = 0; j < 16; j++) acc[j] += kd * vl[eb + j];
    __syncthreads();
  }
  #pragma unroll
  for (int j = 0; j < 16; j++)
    atomicAdd(&kvb[(((size_t)(s * NH + h)) * HD + d) * HD + eb + j], acc[j]);
  if (t < 64) atomicAdd(&ksb[(s * NH + h) * HD + t], acck);
}

// a = num/den per row, register-tiled. grid 256 blocks
__global__ __launch_bounds__(256) void attn_kernel(
    const float* __restrict__ qw, const float* __restrict__ kvb,
    const float* __restrict__ ksb, float* __restrict__ aw)
{
  __shared__ float kvl[64 * 64];   // 16 KB
  __shared__ float ksl[64];
  __shared__ float ql[32 * 64];    // 8 KB
  int t = threadIdx.x, b = blockIdx.x;
  int sh = b >> 4, rb = b & 15;
  int s = sh >> 2, h = sh & 3;
  for (int i = t; i < 4096; i += 256) kvl[i] = kvb[sh * 4096 + i];
  if (t < 64) ksl[t] = ksb[sh * 64 + t];
  for (int i = t; i < 2048; i += 256) {
    int r = i >> 6, d = i & 63;
    ql[i] = qw[((size_t)(s * KSEG + rb * 32 + r)) * 256 + h * 64 + d];
  }
  __syncthreads();
  int e = t & 63, rg = t >> 6;
  float num[8], den[8];
  #pragma unroll
  for (int r = 0; r < 8; r++) { num[r] = 0.f; den[r] = 0.f; }
  #pragma unroll 4
  for (int d4 = 0; d4 < 64; d4 += 4) {
    float4 ks4 = *(const float4*)&ksl[d4];
    float kv0 = kvl[(d4 + 0) * 64 + e];
    float kv1 = kvl[(d4 + 1) * 64 + e];
    float kv2 = kvl[(d4 + 2) * 64 + e];
    float kv3 = kvl[(d4 + 3) * 64 + e];
    #pragma unroll
    for (int r = 0; r < 8; r++) {
      float4 q4 = *(const float4*)&ql[(rg * 8 + r) * 64 + d4];
      num[r] += q4.x * kv0 + q4.y * kv1 + q4.z * kv2 + q4.w * kv3;
      den[r] += q4.x * ks4.x + q4.y * ks4.y + q4.z * ks4.z + q4.w * ks4.w;
    }
  }
  #pragma unroll
  for (int r = 0; r < 8; r++) {
    int row = rb * 32 + rg * 8 + r;
    aw[((size_t)(s * KSEG + row)) * 256 + h * 64 + e] = num[r] / (den[r] + 1e-6f);
  }
}

// x2 = x + a@Wo + bo. grid 256
__global__ __launch_bounds__(256) void oproj_kernel(
    const float* __restrict__ aw, const float* __restrict__ x,
    const float* __restrict__ Wo, const float* __restrict__ bo,
    float* __restrict__ x2)
{
  int rb = blockIdx.x, col = threadIdx.x;
  __shared__ float al[8][256];
  for (int i = threadIdx.x; i < 8 * 256; i += 256)
    al[i >> 8][i & 255] = aw[(rb * 8 + (i >> 8)) * 256 + (i & 255)];
  __syncthreads();
  float acc[8] = {0, 0, 0, 0, 0, 0, 0, 0};
  #pragma unroll 4
  for (int kk = 0; kk < 256; kk++) {
    float wv = Wo[kk * 256 + col];
    #pragma unroll
    for (int r = 0; r < 8; r++) acc[r] += al[r][kk] * wv;
  }
  #pragma unroll
  for (int r = 0; r < 8; r++) {
    int row = rb * 8 + r;
    x2[row * 256 + col] = x[row * 256 + col] + acc[r] + bo[col];
  }
}

// hid = gelu(y2 @ ffn_W1 + b1). grid (256, 4)
__global__ __launch_bounds__(256) void ffn1_kernel(
    const float* __restrict__ y2, const float* __restrict__ W1,
    const float* __restrict__ b1, float* __restrict__ hid)
{
  int rb = blockIdx.x, col = blockIdx.y * 256 + threadIdx.x;
  __shared__ float yl[8][256];
  for (int i = threadIdx.x; i < 8 * 256; i += 256)
    yl[i >> 8][i & 255] = y2[(rb * 8 + (i >> 8)) * 256 + (i & 255)];
  __syncthreads();
  float acc[8] = {0, 0, 0, 0, 0, 0, 0, 0};
  #pragma unroll 4
  for (int kk = 0; kk < 256; kk++) {
    float wv = W1[kk * FF + col];
    #pragma unroll
    for (int r = 0; r < 8; r++) acc[r] += yl[r][kk] * wv;
  }
  #pragma unroll
  for (int r = 0; r < 8; r++)
    hid[(size_t)(rb * 8 + r) * FF + col] = gelu_f(acc[r] + b1[col]);
}

// psu = x2 + hid @ ffn_W2 + b2 ; also psu_bf16. grid 256
__global__ __launch_bounds__(256) void ffn2_kernel(
    const float* __restrict__ hid, const float* __restrict__ x2,
    const float* __restrict__ W2, const float* __restrict__ b2,
    float* __restrict__ psu_out, unsigned short* __restrict__ psub)
{
  int rb = blockIdx.x, col = threadIdx.x;
  __shared__ float hl[8][FF];  // 32KB
  for (int i = threadIdx.x; i < 8 * FF; i += 256)
    hl[i >> 10][i & 1023] = hid[(size_t)(rb * 8 + (i >> 10)) * FF + (i & 1023)];
  __syncthreads();
  float acc[8] = {0, 0, 0, 0, 0, 0, 0, 0};
  #pragma unroll 4
  for (int kk = 0; kk < FF; kk++) {
    float wv = W2[kk * 256 + col];
    #pragma unroll
    for (int r = 0; r < 8; r++) acc[r] += hl[r][kk] * wv;
  }
  #pragma unroll
  for (int r = 0; r < 8; r++) {
    int row = rb * 8 + r;
    float tv = x2[row * 256 + col] + acc[r] + b2[col];
    psu_out[row * 256 + col] = tv;
    psub[row * 256 + col] = f2bf(tv);
  }
}

// Pre-pack mlp weights to bf16 in MFMA-fragment order.
__global__ __launch_bounds__(256) void wprep_kernel(
    const float* __restrict__ mW1, const float* __restrict__ mW2,
    unsigned short* __restrict__ W1f, unsigned short* __restrict__ W2f)
{
  int i = blockIdx.x * 256 + threadIdx.x;
  if (i < 131072) {
    int tile = i >> 9, idx = i & 511;
    int lane = idx >> 3, j = idx & 7;
    int c = tile >> 4, kc = tile & 15;
    int k = kc * 32 + (lane >> 4) * 8 + j;
    int col = c * 16 + (lane & 15);
    W1f[i] = f2bf(mW1[k * 256 + col]);
  } else {
    int i2 = i - 131072;
    int tile = i2 >> 9, idx = i2 & 511;
    int lane = idx >> 3, j = idx & 7;
    int c = tile >> 3, kc = tile & 7;
    int k = kc * 32 + (lane >> 4) * 8 + j;
    int col = c * 16 + (lane & 15);
    W2f[i2] = f2bf(mW2[k * 256 + col]);
  }
}

// ---------------- Phase C: fused node MLP (bf16 MFMA) ----------------
#define AP 520   // A row stride (bf16): 512 + 8 pad
#define HP 264   // hid row stride (bf16): 256 + 8 pad
#define CP 260   // C row stride (f32): 256 + 4 pad
__global__ __launch_bounds__(256, 2) void node_mlp_kernel(
    const float* __restrict__ H, const int* __restrict__ pids,
    const unsigned short* __restrict__ psub,
    const unsigned short* __restrict__ W1f, const unsigned short* __restrict__ W2f,
    const float* __restrict__ b1, const float* __restrict__ b2,
    float* __restrict__ out)
{
  __shared__ __align__(16) unsigned char smem[64 * AP * 2];  // 66560 B
  unsigned short* Albs = (unsigned short*)smem;
  unsigned short* Hlds = (unsigned short*)smem;
  float* Cl = (float*)smem;
  int tid = threadIdx.x;
  int lane = tid & 63, w = tid >> 6;
  int ln15 = lane & 15, hi = lane >> 4;
  int base = blockIdx.x * 64;

  for (int i = tid; i < 64 * 64; i += 256) {
    int r = i >> 6, c4 = i & 63;
    float4 f = *(const float4*)(H + ((size_t)(base + r)) * 256 + c4 * 4);
    unsigned int lo = (unsigned int)f2bf(f.x) | ((unsigned int)f2bf(f.y) << 16);
    unsigned int hi2 = (unsigned int)f2bf(f.z) | ((unsigned int)f2bf(f.w) << 16);
    u32x2 val = {lo, hi2};
    *((u32x2*)&Albs[r * AP + c4 * 4]) = val;
  }
  for (int i = tid; i < 64 * 32; i += 256) {
    int r = i >> 5, ch = i & 31;
    int node = base + r;
    int ss = node >> 15, nn = node & 32767;
    int pid = pids[ss * N + nn];
    *((u32x4*)&Albs[r * AP + 256 + ch * 8]) =
        *(const u32x4*)(psub + ((size_t)(ss * KSEG + pid)) * 256 + ch * 8);
  }
  __syncthreads();

  f32x4 acc[4][4];
  #pragma unroll
  for (int a = 0; a < 4; a++)
    #pragma unroll
    for (int c = 0; c < 4; c++) acc[a][c] = (f32x4){0.f, 0.f, 0.f, 0.f};

  // ---- GEMM1: [64x512] @ [512x256], B streamed from L2 ----
  {
    const unsigned short* Wl = W1f + (size_t)lane * 8;
    short8 bcur[4];
    #pragma unroll
    for (int ct = 0; ct < 4; ct++)
      bcur[ct] = *(const short8*)(Wl + ((w * 4 + ct) * 16 + 0) * 512);
    #pragma unroll
    for (int kc = 0; kc < 16; kc++) {
      short8 a[4], bnext[4];
      #pragma unroll
      for (int rt = 0; rt < 4; rt++)
        a[rt] = *(const short8*)(&Albs[(rt * 16 + ln15) * AP + kc * 32 + hi * 8]);
      if (kc < 15) {
        #pragma unroll
        for (int ct = 0; ct < 4; ct++)
          bnext[ct] = *(const short8*)(Wl + ((w * 4 + ct) * 16 + kc + 1) * 512);
      }
      #pragma unroll
      for (int rt = 0; rt < 4; rt++)
        #pragma unroll
        for (int ct = 0; ct < 4; ct++)
          acc[rt][ct] = __builtin_amdgcn_mfma_f32_16x16x32_bf16(a[rt], bcur[ct], acc[rt][ct], 0, 0, 0);
      if (kc < 15) {
        #pragma unroll
        for (int ct = 0; ct < 4; ct++) bcur[ct] = bnext[ct];
      }
    }
  }

  __syncthreads();

  #pragma unroll
  for (int rt = 0; rt < 4; rt++) {
    #pragma unroll
    for (int ct = 0; ct < 4; ct++) {
      int col = w * 64 + ct * 16 + ln15;
      float bb = b1[col];
      #pragma unroll
      for (int r = 0; r < 4; r++) {
        int row = rt * 16 + hi * 4 + r;
        Hlds[row * HP + col] = f2bf(gelu_f(acc[rt][ct][r] + bb));
      }
      acc[rt][ct] = (f32x4){0.f, 0.f, 0.f, 0.f};
    }
  }
  __syncthreads();

  // ---- GEMM2: [64x256] @ [256x256], B streamed from L2 ----
  {
    const unsigned short* Wl = W2f + (size_t)lane * 8;
    short8 bcur[4];
    #pragma unroll
    for (int ct = 0; ct < 4; ct++)
      bcur[ct] = *(const short8*)(Wl + ((w * 4 + ct) * 8 + 0) * 512);
    #pragma unroll
    for (int kc = 0; kc < 8; kc++) {
      short8 a[4], bnext[4];
      #pragma unroll
      for (int rt = 0; rt < 4; rt++)
        a[rt] = *(const short8*)(&Hlds[(rt * 16 + ln15) * HP + kc * 32 + hi * 8]);
      if (kc < 7) {
        #pragma unroll
        for (int ct = 0; ct < 4; ct++)
          bnext[ct] = *(const short8*)(Wl + ((w * 4 + ct) * 8 + kc + 1) * 512);
      }
      #pragma unroll
      for (int rt = 0; rt < 4; rt++)
        #pragma unroll
        for (int ct = 0; ct < 4; ct++)
          acc[rt][ct] = __builtin_amdgcn_mfma_f32_16x16x32_bf16(a[rt], bcur[ct], acc[rt][ct], 0, 0, 0);
      if (kc < 7) {
        #pragma unroll
        for (int ct = 0; ct < 4; ct++) bcur[ct] = bnext[ct];
      }
    }
  }

  __syncthreads();

  #pragma unroll
  for (int rt = 0; rt < 4; rt++) {
    #pragma unroll
    for (int ct = 0; ct < 4; ct++) {
      int col = w * 64 + ct * 16 + ln15;
      float bb = b2[col];
      #pragma unroll
      for (int r = 0; r < 4; r++)
        Cl[(rt * 16 + hi * 4 + r) * CP + col] = acc[rt][ct][r] + bb;
    }
  }
  __syncthreads();

  for (int i = tid; i < 64 * 64; i += 256) {
    int r = i >> 6, c4 = i & 63;
    size_t gidx = ((size_t)(base + r)) * 256 + c4 * 4;
    float4 h4 = *(const float4*)(H + gidx);
    float4 cv = *(const float4*)&Cl[r * CP + c4 * 4];
    float4 o4 = {h4.x + cv.x, h4.y + cv.y, h4.z + cv.z, h4.w + cv.w};
    *(float4*)(out + gidx) = o4;
  }
}

extern "C" void kernel_launch(void* const* d_in, const int* in_sizes, int n_in,
                              void* d_out, int out_size, void* d_ws, size_t ws_size,
                              hipStream_t stream) {
  (void)in_sizes; (void)n_in; (void)out_size; (void)ws_size;
  const float* H    = (const float*)d_in[0];
  const int*   pids = (const int*)d_in[1];
  const float* ln1g = (const float*)d_in[2];
  const float* ln1b = (const float*)d_in[3];
  const float* Wq   = (const float*)d_in[4];
  const float* bq   = (const float*)d_in[5];
  const float* Wk   = (const float*)d_in[6];
  const float* bk   = (const float*)d_in[7];
  const float* Wv   = (const float*)d_in[8];
  const float* bv   = (const float*)d_in[9];
  const float* Wo   = (const float*)d_in[10];
  const float* bo   = (const float*)d_in[11];
  const float* ln2g = (const float*)d_in[12];
  const float* ln2b = (const float*)d_in[13];
  const float* fW1  = (const float*)d_in[14];
  const float* fb1  = (const float*)d_in[15];
  const float* fW2  = (const float*)d_in[16];
  const float* fb2  = (const float*)d_in[17];
  const float* mW1  = (const float*)d_in[18];
  const float* mb1  = (const float*)d_in[19];
  const float* mW2  = (const float*)d_in[20];
  const float* mb2  = (const float*)d_in[21];
  float* out = (float*)d_out;
  float* ws = (float*)d_ws;

  // sort scratch (re-using old sums slot region)
  int*   histc   = (int*)ws;                         // 32768 ints
  int*   segstart= (int*)(ws + 32768);               // 2048
  int*   cnti    = (int*)(ws + 34816);               // 2048
  int*   order   = (int*)(ws + 36864);               // 131072
  float* counts  = ws + 524288;                      // 2048
  float* xw      = ws + 526336;                      // 524288
  float* yw      = ws + 1050624;                     // 524288
  float* qw      = ws + 1574912;                     // 524288
  float* kw      = ws + 2099200;                     // 524288
  float* vw      = ws + 2623488;                     // 524288
  float* kvb     = ws + 3147776;                     // 65536
  float* ksb     = ws + 3213312;                     // 1024
  float* aw      = ws + 3214336;                     // 524288
  float* x2w     = ws + 3738624;                     // 524288
  float* y2w     = ws + 4262912;                     // 524288
  float* hidw    = ws + 4787200;                     // 2097152
  unsigned short* psub = (unsigned short*)(ws + 6884352);  // 524288 bf16
  unsigned short* W1f  = (unsigned short*)(ws + 7146496);  // 131072 bf16
  unsigned short* W2f  = (unsigned short*)(ws + 7212032);  // 65536 bf16

  hipMemsetAsync(kvb, 0, (65536 + 1024) * sizeof(float), stream);

  wprep_kernel<<<768, 256, 0, stream>>>(mW1, mW2, W1f, W2f);
  hist_kernel<<<64, 256, 0, stream>>>(pids, histc);
  prefix_kernel<<<4, 256, 0, stream>>>(histc, segstart, cnti, counts);
  scatter_kernel<<<64, 256, 0, stream>>>(pids, histc, order);
  pool_gather<<<512, 256, 0, stream>>>(H, order, segstart, cnti, xw);
  pool_ln_kernel<<<2048, 256, 0, stream>>>(xw, ln1g, ln1b, yw);
  qkv_kernel<<<dim3(256, 3), 256, 0, stream>>>(yw, counts, Wq, bq, Wk, bk, Wv, bv, qw, kw, vw);
  kv_kernel<<<128, 256, 0, stream>>>(kw, vw, kvb, ksb);
  attn_kernel<<<256, 256, 0, stream>>>(qw, kvb, ksb, aw);
  oproj_kernel<<<256, 256, 0, stream>>>(aw, xw, Wo, bo, x2w);
  ln_kernel<<<2048, 256, 0, stream>>>(x2w, y2w, ln2g, ln2b);
  ffn1_kernel<<<dim3(256, 4), 256, 0, stream>>>(y2w, fW1, fb1, hidw);
  ffn2_kernel<<<256, 256, 0, stream>>>(hidw, x2w, fW2, fb2, out + (size_t)S * N * D, psub);
  node_mlp_kernel<<<2048, 256, 0, stream>>>(H, pids, psub, W1f, W2f, mb1, mb2, out);
}

// Round 5
// 444.587 us; speedup vs baseline: 1.9029x; 1.0059x over previous
//
#include <hip/hip_runtime.h>
#include <hip/hip_bf16.h>

#define S 4
#define N 32768
#define D 256
#define KSEG 512
#define NH 4
#define HD 64
#define FF 1024

typedef __attribute__((ext_vector_type(8))) short short8;
typedef __attribute__((ext_vector_type(4))) float f32x4;
typedef __attribute__((ext_vector_type(4))) unsigned int u32x4;
typedef __attribute__((ext_vector_type(2))) unsigned int u32x2;

__device__ __forceinline__ unsigned short f2bf(float f) {
  union { __hip_bfloat16 h; unsigned short u; } cv;
  cv.h = __float2bfloat16(f);
  return cv.u;
}

__device__ __forceinline__ float gelu_f(float x) {
  return 0.5f * x * (1.0f + erff(x * 0.70710678118654752440f));
}

__device__ __forceinline__ float wave_reduce_sum(float v) {
  #pragma unroll
  for (int o = 32; o > 0; o >>= 1) v += __shfl_xor(v, o, 64);
  return v;
}

// ---------------- Phase A: counting sort by patch id ----------------
// 1) per-(s,chunk) histogram. grid 64 = 4 s x 16 chunks
__global__ __launch_bounds__(256) void hist_kernel(
    const int* __restrict__ pids, int* __restrict__ histc)
{
  __shared__ int h[KSEG];
  int b = blockIdx.x, t = threadIdx.x;
  int s = b >> 4, c = b & 15;
  for (int i = t; i < KSEG; i += 256) h[i] = 0;
  __syncthreads();
  const int* p = pids + s * N + c * 2048;
  for (int i = t; i < 2048; i += 256) atomicAdd(&h[p[i]], 1);
  __syncthreads();
  for (int i = t; i < KSEG; i += 256) histc[(s * 16 + c) * KSEG + i] = h[i];
}

// 2) per-sample: counts, exclusive bin scan, per-chunk bases (in-place into histc).
__global__ __launch_bounds__(256) void prefix_kernel(
    int* __restrict__ histc, int* __restrict__ segstart,
    int* __restrict__ cnti, float* __restrict__ counts)
{
  __shared__ int h[16 * KSEG];   // 32 KB
  __shared__ int sc[KSEG];
  __shared__ int sa[KSEG], sb[KSEG];
  int s = blockIdx.x, t = threadIdx.x;
  for (int i = t; i < 16 * KSEG; i += 256) h[i] = histc[s * 16 * KSEG + i];
  __syncthreads();
  #pragma unroll
  for (int u = 0; u < 2; u++) {
    int bin = t + u * 256;
    int cc = 0;
    #pragma unroll
    for (int c = 0; c < 16; c++) cc += h[c * KSEG + bin];
    sc[bin] = cc;
    sa[bin] = cc;
  }
  __syncthreads();
  int* src = sa; int* dst = sb;
  for (int off = 1; off < KSEG; off <<= 1) {
    #pragma unroll
    for (int u = 0; u < 2; u++) {
      int bin = t + u * 256;
      int v = src[bin];
      if (bin >= off) v += src[bin - off];
      dst[bin] = v;
    }
    __syncthreads();
    int* tmp = src; src = dst; dst = tmp;
  }
  #pragma unroll
  for (int u = 0; u < 2; u++) {
    int bin = t + u * 256;
    int cc = sc[bin];
    int excl = src[bin] - cc;
    segstart[s * KSEG + bin] = excl;
    cnti[s * KSEG + bin] = cc;
    counts[s * KSEG + bin] = (float)cc;
    int run = excl;
    #pragma unroll
    for (int c = 0; c < 16; c++) {
      int v = h[c * KSEG + bin];
      h[c * KSEG + bin] = run;
      run += v;
    }
  }
  __syncthreads();
  for (int i = t; i < 16 * KSEG; i += 256) histc[s * 16 * KSEG + i] = h[i];
}

// 3) scatter node rows into segment-sorted order. grid 64
__global__ __launch_bounds__(256) void scatter_kernel(
    const int* __restrict__ pids, const int* __restrict__ histc,
    int* __restrict__ order)
{
  __shared__ int offs[KSEG];
  int b = blockIdx.x, t = threadIdx.x;
  int s = b >> 4, c = b & 15;
  for (int i = t; i < KSEG; i += 256) offs[i] = histc[(s * 16 + c) * KSEG + i];
  __syncthreads();
  const int* p = pids + s * N + c * 2048;
  for (int i = t; i < 2048; i += 256) {
    int pid = p[i];
    int pos = atomicAdd(&offs[pid], 1);
    order[s * N + pos] = s * N + c * 2048 + i;
  }
}

// 4) gather-reduce: one wave per segment, coalesced float4 row streams.
__global__ __launch_bounds__(256) void pool_gather(
    const float* __restrict__ H, const int* __restrict__ order,
    const int* __restrict__ segstart, const int* __restrict__ cnti,
    float* __restrict__ xw)
{
  int tid = threadIdx.x;
  int w = tid >> 6, lane = tid & 63;
  int seg = blockIdx.x * 4 + w;
  int s = seg >> 9;
  int st = segstart[seg], cn = cnti[seg];
  int en = st + cn;
  const int* ord = order + (size_t)s * N;
  int c4 = lane << 2;
  f32x4 a0 = {0,0,0,0}, a1 = {0,0,0,0}, a2 = {0,0,0,0}, a3 = {0,0,0,0};
  f32x4 a4 = {0,0,0,0}, a5 = {0,0,0,0}, a6 = {0,0,0,0}, a7 = {0,0,0,0};
  int i = st;
  for (; i + 8 <= en; i += 8) {
    int r0 = ord[i + 0], r1 = ord[i + 1], r2 = ord[i + 2], r3 = ord[i + 3];
    int r4 = ord[i + 4], r5 = ord[i + 5], r6 = ord[i + 6], r7 = ord[i + 7];
    a0 += *(const f32x4*)(H + (size_t)r0 * 256 + c4);
    a1 += *(const f32x4*)(H + (size_t)r1 * 256 + c4);
    a2 += *(const f32x4*)(H + (size_t)r2 * 256 + c4);
    a3 += *(const f32x4*)(H + (size_t)r3 * 256 + c4);
    a4 += *(const f32x4*)(H + (size_t)r4 * 256 + c4);
    a5 += *(const f32x4*)(H + (size_t)r5 * 256 + c4);
    a6 += *(const f32x4*)(H + (size_t)r6 * 256 + c4);
    a7 += *(const f32x4*)(H + (size_t)r7 * 256 + c4);
  }
  for (; i < en; i++) {
    int r = ord[i];
    a0 += *(const f32x4*)(H + (size_t)r * 256 + c4);
  }
  f32x4 ssum = ((a0 + a1) + (a2 + a3)) + ((a4 + a5) + (a6 + a7));
  float inv = 1.f / fmaxf((float)cn, 1.f);
  ssum = ssum * inv;
  *(f32x4*)(xw + (size_t)seg * 256 + c4) = ssum;
}

// y = LN(x). grid 2048 rows
__global__ __launch_bounds__(256) void pool_ln_kernel(
    const float* __restrict__ xw,
    const float* __restrict__ g, const float* __restrict__ b,
    float* __restrict__ yw)
{
  int row = blockIdx.x, t = threadIdx.x;
  float v = xw[row * 256 + t];
  float s1 = wave_reduce_sum(v);
  float s2 = wave_reduce_sum(v * v);
  __shared__ float a1[4], a2[4];
  int w = t >> 6;
  if ((t & 63) == 0) { a1[w] = s1; a2[w] = s2; }
  __syncthreads();
  float ts1 = a1[0] + a1[1] + a1[2] + a1[3];
  float ts2 = a2[0] + a2[1] + a2[2] + a2[3];
  float mu = ts1 * (1.f / 256.f);
  float var = ts2 * (1.f / 256.f) - mu * mu;
  yw[row * 256 + t] = (v - mu) * rsqrtf(var + 1e-5f) * g[t] + b[t];
}

// LayerNorm per row. grid 2048 rows
__global__ __launch_bounds__(256) void ln_kernel(
    const float* __restrict__ in, float* __restrict__ outp,
    const float* __restrict__ g, const float* __restrict__ b)
{
  int row = blockIdx.x, t = threadIdx.x;
  float v = in[row * 256 + t];
  float s1 = wave_reduce_sum(v);
  float s2 = wave_reduce_sum(v * v);
  __shared__ float a1[4], a2[4];
  int w = t >> 6;
  if ((t & 63) == 0) { a1[w] = s1; a2[w] = s2; }
  __syncthreads();
  float ts1 = a1[0] + a1[1] + a1[2] + a1[3];
  float ts2 = a2[0] + a2[1] + a2[2] + a2[3];
  float mu = ts1 * (1.f / 256.f);
  float var = ts2 * (1.f / 256.f) - mu * mu;
  outp[row * 256 + t] = (v - mu) * rsqrtf(var + 1e-5f) * g[t] + b[t];
}

// QKV projections + phi + mask. grid (256, 3)
__global__ __launch_bounds__(256) void qkv_kernel(
    const float* __restrict__ y, const float* __restrict__ counts,
    const float* __restrict__ Wq, const float* __restrict__ bq,
    const float* __restrict__ Wk, const float* __restrict__ bk,
    const float* __restrict__ Wv, const float* __restrict__ bv,
    float* __restrict__ qo, float* __restrict__ ko, float* __restrict__ vo)
{
  int m = blockIdx.y;
  const float* W = (m == 0) ? Wq : ((m == 1) ? Wk : Wv);
  const float* bias = (m == 0) ? bq : ((m == 1) ? bk : bv);
  float* outp = (m == 0) ? qo : ((m == 1) ? ko : vo);
  int rb = blockIdx.x, col = threadIdx.x;
  __shared__ float yl[8][256];
  for (int i = threadIdx.x; i < 8 * 256; i += 256)
    yl[i >> 8][i & 255] = y[(rb * 8 + (i >> 8)) * 256 + (i & 255)];
  __syncthreads();
  float acc[8] = {0, 0, 0, 0, 0, 0, 0, 0};
  #pragma unroll 8
  for (int kk = 0; kk < 256; kk++) {
    float wv = W[kk * 256 + col];
    #pragma unroll
    for (int r = 0; r < 8; r++) acc[r] += yl[r][kk] * wv;
  }
  #pragma unroll
  for (int r = 0; r < 8; r++) {
    int row = rb * 8 + r;
    float tv = acc[r] + bias[col];
    if (m <= 1) tv = (tv > 0.f) ? (tv + 1.f) : expf(tv);   // phi = elu+1
    if (m >= 1) tv *= (counts[row] > 0.f) ? 1.f : 0.f;     // mask on k,v
    outp[row * 256 + col] = tv;
  }
}

// kv[s,h,d,e] = sum_k k*v ; ksum[s,h,d]. grid 128 blocks
__global__ __launch_bounds__(256) void kv_kernel(
    const float* __restrict__ kw, const float* __restrict__ vw,
    float* __restrict__ kvb, float* __restrict__ ksb)
{
  int b = blockIdx.x, t = threadIdx.x;
  int s = b / (NH * 8), h = (b / 8) % NH, ck = b & 7;
  __shared__ float kl[64], vl[64];
  float acc[16];
  #pragma unroll
  for (int j = 0; j < 16; j++) acc[j] = 0.f;
  float acck = 0.f;
  int d = t & 63, eb = (t >> 6) * 16;
  for (int kk = ck * 64; kk < ck * 64 + 64; kk++) {
    if (t < 64) kl[t] = kw[((size_t)(s * KSEG + kk) * NH + h) * HD + t];
    else if (t < 128) vl[t - 64] = vw[((size_t)(s * KSEG + kk) * NH + h) * HD + (t - 64)];
    __syncthreads();
    float kd = kl[d];
    if (t < 64) acck += kd;
    #pragma unroll
    for (int j = 0; j < 16; j++) acc[j] += kd * vl[eb + j];
    __syncthreads();
  }
  #pragma unroll
  for (int j = 0; j < 16; j++)
    atomicAdd(&kvb[(((size_t)(s * NH + h)) * HD + d) * HD + eb + j], acc[j]);
  if (t < 64) atomicAdd(&ksb[(s * NH + h) * HD + t], acck);
}

// a = num/den per row, register-tiled. grid 256 blocks
__global__ __launch_bounds__(256) void attn_kernel(
    const float* __restrict__ qw, const float* __restrict__ kvb,
    const float* __restrict__ ksb, float* __restrict__ aw)
{
  __shared__ float kvl[64 * 64];   // 16 KB
  __shared__ float ksl[64];
  __shared__ float ql[32 * 64];    // 8 KB
  int t = threadIdx.x, b = blockIdx.x;
  int sh = b >> 4, rb = b & 15;
  int s = sh >> 2, h = sh & 3;
  for (int i = t; i < 4096; i += 256) kvl[i] = kvb[sh * 4096 + i];
  if (t < 64) ksl[t] = ksb[sh * 64 + t];
  for (int i = t; i < 2048; i += 256) {
    int r = i >> 6, d = i & 63;
    ql[i] = qw[((size_t)(s * KSEG + rb * 32 + r)) * 256 + h * 64 + d];
  }
  __syncthreads();
  int e = t & 63, rg = t >> 6;
  float num[8], den[8];
  #pragma unroll
  for (int r = 0; r < 8; r++) { num[r] = 0.f; den[r] = 0.f; }
  #pragma unroll 4
  for (int d4 = 0; d4 < 64; d4 += 4) {
    float4 ks4 = *(const float4*)&ksl[d4];
    float kv0 = kvl[(d4 + 0) * 64 + e];
    float kv1 = kvl[(d4 + 1) * 64 + e];
    float kv2 = kvl[(d4 + 2) * 64 + e];
    float kv3 = kvl[(d4 + 3) * 64 + e];
    #pragma unroll
    for (int r = 0; r < 8; r++) {
      float4 q4 = *(const float4*)&ql[(rg * 8 + r) * 64 + d4];
      num[r] += q4.x * kv0 + q4.y * kv1 + q4.z * kv2 + q4.w * kv3;
      den[r] += q4.x * ks4.x + q4.y * ks4.y + q4.z * ks4.z + q4.w * ks4.w;
    }
  }
  #pragma unroll
  for (int r = 0; r < 8; r++) {
    int row = rb * 32 + rg * 8 + r;
    aw[((size_t)(s * KSEG + row)) * 256 + h * 64 + e] = num[r] / (den[r] + 1e-6f);
  }
}

// x2 = x + a@Wo + bo. grid 256
__global__ __launch_bounds__(256) void oproj_kernel(
    const float* __restrict__ aw, const float* __restrict__ x,
    const float* __restrict__ Wo, const float* __restrict__ bo,
    float* __restrict__ x2)
{
  int rb = blockIdx.x, col = threadIdx.x;
  __shared__ float al[8][256];
  for (int i = threadIdx.x; i < 8 * 256; i += 256)
    al[i >> 8][i & 255] = aw[(rb * 8 + (i >> 8)) * 256 + (i & 255)];
  __syncthreads();
  float acc[8] = {0, 0, 0, 0, 0, 0, 0, 0};
  #pragma unroll 8
  for (int kk = 0; kk < 256; kk++) {
    float wv = Wo[kk * 256 + col];
    #pragma unroll
    for (int r = 0; r < 8; r++) acc[r] += al[r][kk] * wv;
  }
  #pragma unroll
  for (int r = 0; r < 8; r++) {
    int row = rb * 8 + r;
    x2[row * 256 + col] = x[row * 256 + col] + acc[r] + bo[col];
  }
}

// hid = gelu(y2 @ ffn_W1 + b1). grid (256, 4)
__global__ __launch_bounds__(256) void ffn1_kernel(
    const float* __restrict__ y2, const float* __restrict__ W1,
    const float* __restrict__ b1, float* __restrict__ hid)
{
  int rb = blockIdx.x, col = blockIdx.y * 256 + threadIdx.x;
  __shared__ float yl[8][256];
  for (int i = threadIdx.x; i < 8 * 256; i += 256)
    yl[i >> 8][i & 255] = y2[(rb * 8 + (i >> 8)) * 256 + (i & 255)];
  __syncthreads();
  float acc[8] = {0, 0, 0, 0, 0, 0, 0, 0};
  #pragma unroll 8
  for (int kk = 0; kk < 256; kk++) {
    float wv = W1[kk * FF + col];
    #pragma unroll
    for (int r = 0; r < 8; r++) acc[r] += yl[r][kk] * wv;
  }
  #pragma unroll
  for (int r = 0; r < 8; r++)
    hid[(size_t)(rb * 8 + r) * FF + col] = gelu_f(acc[r] + b1[col]);
}

// psu = x2 + hid @ ffn_W2 + b2 ; also psu_bf16. grid 256
__global__ __launch_bounds__(256) void ffn2_kernel(
    const float* __restrict__ hid, const float* __restrict__ x2,
    const float* __restrict__ W2, const float* __restrict__ b2,
    float* __restrict__ psu_out, unsigned short* __restrict__ psub)
{
  int rb = blockIdx.x, col = threadIdx.x;
  __shared__ float hl[8][FF];  // 32KB
  for (int i = threadIdx.x; i < 8 * FF; i += 256)
    hl[i >> 10][i & 1023] = hid[(size_t)(rb * 8 + (i >> 10)) * FF + (i & 1023)];
  __syncthreads();
  float acc[8] = {0, 0, 0, 0, 0, 0, 0, 0};
  #pragma unroll 8
  for (int kk = 0; kk < FF; kk++) {
    float wv = W2[kk * 256 + col];
    #pragma unroll
    for (int r = 0; r < 8; r++) acc[r] += hl[r][kk] * wv;
  }
  #pragma unroll
  for (int r = 0; r < 8; r++) {
    int row = rb * 8 + r;
    float tv = x2[row * 256 + col] + acc[r] + b2[col];
    psu_out[row * 256 + col] = tv;
    psub[row * 256 + col] = f2bf(tv);
  }
}

// Pre-pack mlp weights to bf16 in MFMA-fragment order.
__global__ __launch_bounds__(256) void wprep_kernel(
    const float* __restrict__ mW1, const float* __restrict__ mW2,
    unsigned short* __restrict__ W1f, unsigned short* __restrict__ W2f)
{
  int i = blockIdx.x * 256 + threadIdx.x;
  if (i < 131072) {
    int tile = i >> 9, idx = i & 511;
    int lane = idx >> 3, j = idx & 7;
    int c = tile >> 4, kc = tile & 15;
    int k = kc * 32 + (lane >> 4) * 8 + j;
    int col = c * 16 + (lane & 15);
    W1f[i] = f2bf(mW1[k * 256 + col]);
  } else {
    int i2 = i - 131072;
    int tile = i2 >> 9, idx = i2 & 511;
    int lane = idx >> 3, j = idx & 7;
    int c = tile >> 3, kc = tile & 7;
    int k = kc * 32 + (lane >> 4) * 8 + j;
    int col = c * 16 + (lane & 15);
    W2f[i2] = f2bf(mW2[k * 256 + col]);
  }
}

// ---------------- Phase C: fused node MLP (bf16 MFMA) ----------------
// out = H + gelu([H, psu[pid]] @ mW1 + mb1) @ mW2 + mb2
// grid 2048 blocks (64 rows), 256 threads (4 waves x 4x4 frags).
// LDS 33792 B -> 4 blocks/CU, 16 waves/CU. A staged in two K-halves over one
// buffer; Hid aliases it; C epilogue via two 32-row f32 passes.
#define AP2 264  // A/Hid row stride (bf16): 256 + 8 pad
#define CP2 260  // C row stride (f32): 256 + 4 pad (32-row half)
__global__ __launch_bounds__(256, 4) void node_mlp_kernel(
    const float* __restrict__ H, const int* __restrict__ pids,
    const unsigned short* __restrict__ psub,
    const unsigned short* __restrict__ W1f, const unsigned short* __restrict__ W2f,
    const float* __restrict__ b1, const float* __restrict__ b2,
    float* __restrict__ out)
{
  __shared__ __align__(16) unsigned char smem[64 * AP2 * 2];  // 33792 B
  unsigned short* Ah = (unsigned short*)smem;   // A half / Hid (bf16)
  float* Cl = (float*)smem;                     // C half (f32), 32 rows
  int tid = threadIdx.x;
  int lane = tid & 63, w = tid >> 6;
  int ln15 = lane & 15, hi = lane >> 4;
  int base = blockIdx.x * 64;

  f32x4 acc[4][4];
  #pragma unroll
  for (int a = 0; a < 4; a++)
    #pragma unroll
    for (int c = 0; c < 4; c++) acc[a][c] = (f32x4){0.f, 0.f, 0.f, 0.f};

  // ---- stage A half 1: H part (cols 0..255), fp32 -> bf16 ----
  for (int i = tid; i < 64 * 64; i += 256) {
    int r = i >> 6, c4 = i & 63;
    float4 f = *(const float4*)(H + ((size_t)(base + r)) * 256 + c4 * 4);
    unsigned int lo = (unsigned int)f2bf(f.x) | ((unsigned int)f2bf(f.y) << 16);
    unsigned int hi2 = (unsigned int)f2bf(f.z) | ((unsigned int)f2bf(f.w) << 16);
    u32x2 val = {lo, hi2};
    *((u32x2*)&Ah[r * AP2 + c4 * 4]) = val;
  }
  __syncthreads();

  const unsigned short* Wl1 = W1f + (size_t)lane * 8;
  // ---- GEMM1 kc 0..7 (K 0..255) ----
  {
    short8 bcur[4];
    #pragma unroll
    for (int ct = 0; ct < 4; ct++)
      bcur[ct] = *(const short8*)(Wl1 + ((w * 4 + ct) * 16 + 0) * 512);
    #pragma unroll
    for (int kc = 0; kc < 8; kc++) {
      short8 a[4], bnext[4];
      #pragma unroll
      for (int rt = 0; rt < 4; rt++)
        a[rt] = *(const short8*)(&Ah[(rt * 16 + ln15) * AP2 + kc * 32 + hi * 8]);
      #pragma unroll
      for (int ct = 0; ct < 4; ct++)
        bnext[ct] = *(const short8*)(Wl1 + ((w * 4 + ct) * 16 + kc + 1) * 512);
      #pragma unroll
      for (int rt = 0; rt < 4; rt++)
        #pragma unroll
        for (int ct = 0; ct < 4; ct++)
          acc[rt][ct] = __builtin_amdgcn_mfma_f32_16x16x32_bf16(a[rt], bcur[ct], acc[rt][ct], 0, 0, 0);
      #pragma unroll
      for (int ct = 0; ct < 4; ct++) bcur[ct] = bnext[ct];
    }
  }
  __syncthreads();

  // ---- stage A half 2: psu gather (cols 256..511) ----
  for (int i = tid; i < 64 * 32; i += 256) {
    int r = i >> 5, ch = i & 31;
    int node = base + r;
    int ss = node >> 15, nn = node & 32767;
    int pid = pids[ss * N + nn];
    *((u32x4*)&Ah[r * AP2 + ch * 8]) =
        *(const u32x4*)(psub + ((size_t)(ss * KSEG + pid)) * 256 + ch * 8);
  }
  __syncthreads();

  // ---- GEMM1 kc 8..15 (K 256..511) ----
  {
    short8 bcur[4];
    #pragma unroll
    for (int ct = 0; ct < 4; ct++)
      bcur[ct] = *(const short8*)(Wl1 + ((w * 4 + ct) * 16 + 8) * 512);
    #pragma unroll
    for (int kc = 8; kc < 16; kc++) {
      short8 a[4], bnext[4];
      #pragma unroll
      for (int rt = 0; rt < 4; rt++)
        a[rt] = *(const short8*)(&Ah[(rt * 16 + ln15) * AP2 + (kc - 8) * 32 + hi * 8]);
      if (kc < 15) {
        #pragma unroll
        for (int ct = 0; ct < 4; ct++)
          bnext[ct] = *(const short8*)(Wl1 + ((w * 4 + ct) * 16 + kc + 1) * 512);
      }
      #pragma unroll
      for (int rt = 0; rt < 4; rt++)
        #pragma unroll
        for (int ct = 0; ct < 4; ct++)
          acc[rt][ct] = __builtin_amdgcn_mfma_f32_16x16x32_bf16(a[rt], bcur[ct], acc[rt][ct], 0, 0, 0);
      if (kc < 15) {
        #pragma unroll
        for (int ct = 0; ct < 4; ct++) bcur[ct] = bnext[ct];
      }
    }
  }
  __syncthreads();

  // ---- epilogue 1: bias + gelu -> Hid (aliased over Ah) ----
  #pragma unroll
  for (int rt = 0; rt < 4; rt++) {
    #pragma unroll
    for (int ct = 0; ct < 4; ct++) {
      int col = w * 64 + ct * 16 + ln15;
      float bb = b1[col];
      #pragma unroll
      for (int r = 0; r < 4; r++) {
        int row = rt * 16 + hi * 4 + r;
        Ah[row * AP2 + col] = f2bf(gelu_f(acc[rt][ct][r] + bb));
      }
      acc[rt][ct] = (f32x4){0.f, 0.f, 0.f, 0.f};
    }
  }
  __syncthreads();

  // ---- GEMM2: [64x256] @ [256x256] ----
  {
    const unsigned short* Wl2 = W2f + (size_t)lane * 8;
    short8 bcur[4];
    #pragma unroll
    for (int ct = 0; ct < 4; ct++)
      bcur[ct] = *(const short8*)(Wl2 + ((w * 4 + ct) * 8 + 0) * 512);
    #pragma unroll
    for (int kc = 0; kc < 8; kc++) {
      short8 a[4], bnext[4];
      #pragma unroll
      for (int rt = 0; rt < 4; rt++)
        a[rt] = *(const short8*)(&Ah[(rt * 16 + ln15) * AP2 + kc * 32 + hi * 8]);
      if (kc < 7) {
        #pragma unroll
        for (int ct = 0; ct < 4; ct++)
          bnext[ct] = *(const short8*)(Wl2 + ((w * 4 + ct) * 8 + kc + 1) * 512);
      }
      #pragma unroll
      for (int rt = 0; rt < 4; rt++)
        #pragma unroll
        for (int ct = 0; ct < 4; ct++)
          acc[rt][ct] = __builtin_amdgcn_mfma_f32_16x16x32_bf16(a[rt], bcur[ct], acc[rt][ct], 0, 0, 0);
      if (kc < 7) {
        #pragma unroll
        for (int ct = 0; ct < 4; ct++) bcur[ct] = bnext[ct];
      }
    }
  }

  // ---- final epilogue: two 32-row passes through LDS ----
  #pragma unroll
  for (int rh = 0; rh < 2; rh++) {
    __syncthreads();  // Hid reads done (rh=0) / prior out reads done (rh=1)
    #pragma unroll
    for (int rt2 = 0; rt2 < 2; rt2++) {
      int rt = rh * 2 + rt2;
      #pragma unroll
      for (int ct = 0; ct < 4; ct++) {
        int col = w * 64 + ct * 16 + ln15;
        float bb = b2[col];
        #pragma unroll
        for (int r = 0; r < 4; r++)
          Cl[(rt2 * 16 + hi * 4 + r) * CP2 + col] = acc[rt][ct][r] + bb;
      }
    }
    __syncthreads();
    for (int i = tid; i < 32 * 64; i += 256) {
      int r = i >> 6, c4 = i & 63;
      size_t gidx = ((size_t)(base + rh * 32 + r)) * 256 + c4 * 4;
      float4 h4 = *(const float4*)(H + gidx);
      float4 cv = *(const float4*)&Cl[r * CP2 + c4 * 4];
      float4 o4 = {h4.x + cv.x, h4.y + cv.y, h4.z + cv.z, h4.w + cv.w};
      *(float4*)(out + gidx) = o4;
    }
  }
}

extern "C" void kernel_launch(void* const* d_in, const int* in_sizes, int n_in,
                              void* d_out, int out_size, void* d_ws, size_t ws_size,
                              hipStream_t stream) {
  (void)in_sizes; (void)n_in; (void)out_size; (void)ws_size;
  const float* H    = (const float*)d_in[0];
  const int*   pids = (const int*)d_in[1];
  const float* ln1g = (const float*)d_in[2];
  const float* ln1b = (const float*)d_in[3];
  const float* Wq   = (const float*)d_in[4];
  const float* bq   = (const float*)d_in[5];
  const float* Wk   = (const float*)d_in[6];
  const float* bk   = (const float*)d_in[7];
  const float* Wv   = (const float*)d_in[8];
  const float* bv   = (const float*)d_in[9];
  const float* Wo   = (const float*)d_in[10];
  const float* bo   = (const float*)d_in[11];
  const float* ln2g = (const float*)d_in[12];
  const float* ln2b = (const float*)d_in[13];
  const float* fW1  = (const float*)d_in[14];
  const float* fb1  = (const float*)d_in[15];
  const float* fW2  = (const float*)d_in[16];
  const float* fb2  = (const float*)d_in[17];
  const float* mW1  = (const float*)d_in[18];
  const float* mb1  = (const float*)d_in[19];
  const float* mW2  = (const float*)d_in[20];
  const float* mb2  = (const float*)d_in[21];
  float* out = (float*)d_out;
  float* ws = (float*)d_ws;

  int*   histc   = (int*)ws;                         // 32768 ints
  int*   segstart= (int*)(ws + 32768);               // 2048
  int*   cnti    = (int*)(ws + 34816);               // 2048
  int*   order   = (int*)(ws + 36864);               // 131072
  float* counts  = ws + 524288;                      // 2048
  float* xw      = ws + 526336;                      // 524288
  float* yw      = ws + 1050624;                     // 524288
  float* qw      = ws + 1574912;                     // 524288
  float* kw      = ws + 2099200;                     // 524288
  float* vw      = ws + 2623488;                     // 524288
  float* kvb     = ws + 3147776;                     // 65536
  float* ksb     = ws + 3213312;                     // 1024
  float* aw      = ws + 3214336;                     // 524288
  float* x2w     = ws + 3738624;                     // 524288
  float* y2w     = ws + 4262912;                     // 524288
  float* hidw    = ws + 4787200;                     // 2097152
  unsigned short* psub = (unsigned short*)(ws + 6884352);  // 524288 bf16
  unsigned short* W1f  = (unsigned short*)(ws + 7146496);  // 131072 bf16
  unsigned short* W2f  = (unsigned short*)(ws + 7212032);  // 65536 bf16

  hipMemsetAsync(kvb, 0, (65536 + 1024) * sizeof(float), stream);

  wprep_kernel<<<768, 256, 0, stream>>>(mW1, mW2, W1f, W2f);
  hist_kernel<<<64, 256, 0, stream>>>(pids, histc);
  prefix_kernel<<<4, 256, 0, stream>>>(histc, segstart, cnti, counts);
  scatter_kernel<<<64, 256, 0, stream>>>(pids, histc, order);
  pool_gather<<<512, 256, 0, stream>>>(H, order, segstart, cnti, xw);
  pool_ln_kernel<<<2048, 256, 0, stream>>>(xw, ln1g, ln1b, yw);
  qkv_kernel<<<dim3(256, 3), 256, 0, stream>>>(yw, counts, Wq, bq, Wk, bk, Wv, bv, qw, kw, vw);
  kv_kernel<<<128, 256, 0, stream>>>(kw, vw, kvb, ksb);
  attn_kernel<<<256, 256, 0, stream>>>(qw, kvb, ksb, aw);
  oproj_kernel<<<256, 256, 0, stream>>>(aw, xw, Wo, bo, x2w);
  ln_kernel<<<2048, 256, 0, stream>>>(x2w, y2w, ln2g, ln2b);
  ffn1_kernel<<<dim3(256, 4), 256, 0, stream>>>(y2w, fW1, fb1, hidw);
  ffn2_kernel<<<256, 256, 0, stream>>>(hidw, x2w, fW2, fb2, out + (size_t)S * N * D, psub);
  node_mlp_kernel<<<2048, 256, 0, stream>>>(H, pids, psub, W1f, W2f, mb1, mb2, out);
}